// Round 1
// 384.925 us; speedup vs baseline: 1.1178x; 1.1178x over previous
//
#include <hip/hip_runtime.h>
#include <stdint.h>
#include <stddef.h>

// AttnBlock: x[32,32,32,512] fp32 -> groupnorm(32) -> q/k/v 1x1 conv -> attn(seq=1024) -> proj -> +x
// R6: replace 128x128 2-barrier GEMM with 256x256 8-phase pipelined GEMM
// (T2 swizzle + T3/T4 counted-vmcnt + T5 setprio), per the verified 8-phase template.

typedef short bh8 __attribute__((ext_vector_type(8)));   // 8 bf16 payload (4 VGPRs)
typedef __bf16 bf8 __attribute__((ext_vector_type(8)));  // builtin operand type
typedef float f4 __attribute__((ext_vector_type(4)));
typedef unsigned short u16;

#define NB 32
#define HW 1024
#define NC 512
#define NM (NB * HW)   // 32768 rows total

__device__ __forceinline__ u16 f2bf(float f) {
    union { float f; uint32_t u; } v; v.f = f;
    uint32_t r = v.u + 0x7FFFu + ((v.u >> 16) & 1u);  // RNE
    return (u16)(r >> 16);
}
__device__ __forceinline__ float bf2f(u16 h) {
    union { uint32_t u; float f; } v; v.u = ((uint32_t)h) << 16;
    return v.f;
}

using gas_p = const __attribute__((address_space(1))) void*;
using las_p = __attribute__((address_space(3))) void*;

__device__ __forceinline__ void async16(const void* g, void* l) {
    __builtin_amdgcn_global_load_lds((gas_p)g, (las_p)l, 16, 0, 0);
}

__device__ __forceinline__ f4 mfma16(bh8 a, bh8 b, f4 c) {
    return __builtin_amdgcn_mfma_f32_16x16x32_bf16(
        __builtin_bit_cast(bf8, a), __builtin_bit_cast(bf8, b), c, 0, 0, 0);
}

// raw barrier (NOT __syncthreads: that emits vmcnt(0) and kills the pipeline)
__device__ __forceinline__ void wgbar() { asm volatile("s_barrier" ::: "memory"); }
#define VMCNT(N) asm volatile("s_waitcnt vmcnt(" #N ")" ::: "memory")

// ---------------------------------------------------------------- transpose weights
__global__ __launch_bounds__(256) void transpose_weights(
    const float* __restrict__ wq, const float* __restrict__ wk,
    const float* __restrict__ wv, const float* __restrict__ wp,
    u16* __restrict__ wT)
{
    int idx = blockIdx.x * 256 + threadIdx.x;      // 0 .. 4*512*512-1
    int m = idx >> 18;
    int r = idx & 0x3FFFF;                          // r = k*512 + n (coalesced read)
    int k = r >> 9, n = r & 511;
    const float* w = (m == 0) ? wq : (m == 1) ? wk : (m == 2) ? wv : wp;
    wT[((size_t)m << 18) + (size_t)n * 512 + k] = f2bf(w[r]);
}

// ---------------------------------------------------------------- group norm (3 stages)
__global__ __launch_bounds__(256) void gn_partial(
    const float* __restrict__ x, float2* __restrict__ part)
{
    const int b = blockIdx.x >> 3, s = blockIdx.x & 7;
    const int t = threadIdx.x;
    const int c0 = (t & 127) * 4;
    const int pr = t >> 7;
    const float* xb = x + (size_t)b * HW * NC + (size_t)(s * 128) * NC + c0;
    float sum = 0.f, sq = 0.f;
#pragma unroll 8
    for (int i = 0; i < 64; ++i) {
        const float4 v = *(const float4*)(xb + (size_t)(pr + i * 2) * NC);
        sum += v.x + v.y + v.z + v.w;
        sq  += v.x * v.x + v.y * v.y + v.z * v.z + v.w * v.w;
    }
    __shared__ float2 red[256];
    red[t] = make_float2(sum, sq);
    __syncthreads();
    if (t < 32) {
        float S = 0.f, Q = 0.f;
#pragma unroll
        for (int p = 0; p < 2; ++p)
#pragma unroll
            for (int j = 0; j < 4; ++j) {
                const float2 v = red[t * 4 + j + p * 128];
                S += v.x; Q += v.y;
            }
        part[(size_t)blockIdx.x * 32 + t] = make_float2(S, Q);
    }
}

__global__ __launch_bounds__(256) void gn_stats(
    const float2* __restrict__ part, float2* __restrict__ stats)
{
    const int p = blockIdx.x * 256 + threadIdx.x;   // 0..1023
    const int b = p >> 5, g = p & 31;
    float S = 0.f, Q = 0.f;
#pragma unroll
    for (int s = 0; s < 8; ++s) {
        const float2 v = part[((size_t)(b * 8 + s)) * 32 + g];
        S += v.x; Q += v.y;
    }
    const float mean = S * (1.f / 16384.f);
    const float var = Q * (1.f / 16384.f) - mean * mean;
    stats[p] = make_float2(mean, rsqrtf(var + 1e-6f));
}

__global__ __launch_bounds__(256) void gn_apply(
    const float* __restrict__ x, const float2* __restrict__ stats,
    const float* __restrict__ scale, const float* __restrict__ bias,
    u16* __restrict__ hn)
{
    const size_t idx = (size_t)blockIdx.x * 256 + threadIdx.x;  // float4 index
    const size_t e = idx * 4;
    const int c0 = (int)(e & 511);
    const int bg = (int)(e >> 19) * 32 + (c0 >> 4);
    const float2 st = stats[bg];
    const float4 v = *(const float4*)(x + e);
    const float4 sc = *(const float4*)(scale + c0);
    const float4 bi = *(const float4*)(bias + c0);
    ushort4 o;
    o.x = f2bf((v.x - st.x) * st.y * sc.x + bi.x);
    o.y = f2bf((v.y - st.x) * st.y * sc.y + bi.y);
    o.z = f2bf((v.z - st.x) * st.y * sc.z + bi.z);
    o.w = f2bf((v.w - st.x) * st.y * sc.w + bi.w);
    *(ushort4*)(hn + e) = o;
}

// ---------------------------------------------------------------- 8-phase 256x256 GEMM
// C[M,N] = A[M,K] * Bt[N,K]^T, bf16 in, fp32 accum. BM=BN=256, BK=64.
// 512 threads = 8 waves (2M x 4N); per wave 128x64 output = 8x4 16x16 frags.
// LDS: 2 K-tile buffers x (A[256][64] + B[256][64]) bf16 = 128 KiB.
// Swizzle: 16B-chunk c at row stored at phys chunk c ^ (row&7); staged via
// pre-swizzled GLOBAL source (global_load_lds dest is linear), read with XOR.
// Schedule: per iteration 2 K-tiles, 8 phases (gray-coded C quadrants);
// each phase stages one 16KB region whose last read was >=2 barriers ago;
// counted vmcnt(4) at phases 4 & 8 (never 0 except final-iter boundary).
//
// Region staging map (steady state, iter it; kt = 2*it):
//  p0: buf1.Aq1 <- kt+1   p1: buf1.Bq0 <- kt+1   (complete current buf1 tile)
//  p2: buf0.Aq0 <- kt+2   p3: buf0.Bq1 <- kt+2   [guard it<NI-1]
//  p4: buf0.Aq1 <- kt+2   p5: buf0.Bq0 <- kt+2   [guard]
//  p6: buf1.Aq0 <- kt+3   p7: buf1.Bq1 <- kt+3   [guard]
// Reads: p0..p3 = buf0 quadrants (0,0),(0,1),(1,1),(1,0); p4..p7 same on buf1.

template <int MAT, int Q>
__device__ __forceinline__ void stage_region(u16* ldsmat, const u16* g, int ldG,
                                             int w, int lane) {
#pragma unroll
    for (int j = 0; j < 2; ++j) {
        const int rowbase = (MAT == 0)
            ? (j * 128 + Q * 64 + w * 8)
            : ((j * 2 + (w >> 2)) * 64 + Q * 32 + (w & 3) * 8);
        const int row = rowbase + (lane >> 3);
        const int c16 = (lane & 7) ^ (lane >> 3);       // inverse swizzle on source
        async16(g + (size_t)row * ldG + (c16 << 3), ldsmat + rowbase * 64);
    }
}

#define PHASE(P, D, QM, QN, SD, SMAT, SQ, SKT, GRD)                                \
    {                                                                              \
        bh8 paf[4][2], pbf[2][2];                                                  \
        _Pragma("unroll") for (int mt = 0; mt < 4; ++mt) {                         \
            const int arow = wm * 128 + (QM) * 64 + mt * 16 + r;                   \
            _Pragma("unroll") for (int kk = 0; kk < 2; ++kk)                       \
                paf[mt][kk] = *(const bh8*)&lds[D][0][arow * 64 +                  \
                    (((kk * 4 + q4) ^ (r & 7)) << 3)];                             \
        }                                                                          \
        _Pragma("unroll") for (int nt = 0; nt < 2; ++nt) {                         \
            const int brow = wn * 64 + (QN) * 32 + nt * 16 + r;                    \
            _Pragma("unroll") for (int kk = 0; kk < 2; ++kk)                       \
                pbf[nt][kk] = *(const bh8*)&lds[D][1][brow * 64 +                  \
                    (((kk * 4 + q4) ^ (r & 7)) << 3)];                             \
        }                                                                          \
        if (!(GRD) || it < NI - 1) {                                               \
            const size_t ko = (size_t)(2 * it + (SKT)) << 6;                       \
            if ((SMAT) == 0) stage_region<0, SQ>(&lds[SD][0][0], A_ + ko, K, wid, lane); \
            else             stage_region<1, SQ>(&lds[SD][1][0], B_ + ko, K, wid, lane); \
        }                                                                          \
        wgbar();                                                                   \
        __builtin_amdgcn_s_setprio(1);                                             \
        _Pragma("unroll") for (int mt = 0; mt < 4; ++mt)                           \
            _Pragma("unroll") for (int nt = 0; nt < 2; ++nt)                       \
                _Pragma("unroll") for (int kk = 0; kk < 2; ++kk)                   \
                    acc[(QM) * 4 + mt][(QN) * 2 + nt] =                            \
                        mfma16(paf[mt][kk], pbf[nt][kk],                           \
                               acc[(QM) * 4 + mt][(QN) * 2 + nt]);                 \
        __builtin_amdgcn_s_setprio(0);                                             \
        if ((P) == 3) { if (it < NI - 1) { VMCNT(4); } else { VMCNT(0); } }        \
        if ((P) == 7) { VMCNT(4); }                                                \
        wgbar();                                                                   \
    }

// MODE 0: bf16 C0 = alpha*acc (batched via blockIdx.z)
// MODE 3: fp32 C0 = acc + b0[col] + resid[row*ldc+col]
// MODE 4: fused QKV: col<1024 -> q/k (seg-strided); col>=1024 -> vT transposed
// SWZ > 0: 1D grid of 8*mper*SWZ blocks; xcd = bid&7; same mapping as before.
template <int MODE, int SWZ>
__global__ __launch_bounds__(512, 2) void gemm8(
    const u16* __restrict__ A, const u16* __restrict__ Bt,
    void* __restrict__ C0, void* __restrict__ C1,
    const float* __restrict__ b0, const float* __restrict__ b1,
    const float* __restrict__ b2, const float* __restrict__ resid,
    int K, int ldc, long strA, long strB, long strC, float alpha)
{
    __shared__ __align__(16) u16 lds[2][2][256 * 64];   // 128 KiB
    const int tid = threadIdx.x;
    const int wid = tid >> 6, lane = tid & 63;
    const int wm = wid >> 2, wn = wid & 3;              // 2 x 4 wave grid
    const int r = lane & 15, q4 = lane >> 4;
    const int z = blockIdx.z;

    int m0, n0;
    if (SWZ > 0) {
        const int g = blockIdx.x;
        const int xcd = g & 7, s = g >> 3;
        const int mper = (int)(gridDim.x >> 3) / SWZ;
        m0 = (xcd * mper + s / SWZ) * 256;
        n0 = (s % SWZ) * 256;
    } else {
        m0 = blockIdx.y * 256;
        n0 = blockIdx.x * 256;
    }

    const u16* A_ = A + (size_t)z * strA + (size_t)m0 * K;
    const u16* B_ = Bt + (size_t)z * strB + (size_t)n0 * K;

    f4 acc[8][4];
#pragma unroll
    for (int ii = 0; ii < 8; ++ii)
#pragma unroll
        for (int jj = 0; jj < 4; ++jj) {
            f4 zr = {0.f, 0.f, 0.f, 0.f};
            acc[ii][jj] = zr;
        }

    const int NI = K >> 7;   // 2 K-tiles (of 64) per iteration; K in {512,1024}

    // prologue: issue order == steady-state p2..p7 (vmcnt counting relies on it)
    stage_region<0, 0>(&lds[0][0][0], A_,      K, wid, lane);  // buf0.Aq0 kt0
    stage_region<1, 1>(&lds[0][1][0], B_,      K, wid, lane);  // buf0.Bq1 kt0
    stage_region<0, 1>(&lds[0][0][0], A_,      K, wid, lane);  // buf0.Aq1 kt0
    stage_region<1, 0>(&lds[0][1][0], B_,      K, wid, lane);  // buf0.Bq0 kt0
    stage_region<0, 0>(&lds[1][0][0], A_ + 64, K, wid, lane);  // buf1.Aq0 kt1
    stage_region<1, 1>(&lds[1][1][0], B_ + 64, K, wid, lane);  // buf1.Bq1 kt1
    VMCNT(4);   // buf0 fully landed; buf1.Aq0/Bq1 may remain in flight
    wgbar();

    for (int it = 0; it < NI; ++it) {
        PHASE(0, 0, 0, 0, 1, 0, 1, 1, 0)
        PHASE(1, 0, 0, 1, 1, 1, 0, 1, 0)
        PHASE(2, 0, 1, 1, 0, 0, 0, 2, 1)
        PHASE(3, 0, 1, 0, 0, 1, 1, 2, 1)
        PHASE(4, 1, 0, 0, 0, 0, 1, 2, 1)
        PHASE(5, 1, 0, 1, 0, 1, 0, 2, 1)
        PHASE(6, 1, 1, 1, 1, 0, 0, 3, 1)
        PHASE(7, 1, 1, 0, 1, 1, 1, 3, 1)
    }

    // epilogue: C/D layout col = lane&15, row = (lane>>4)*4 + i
#pragma unroll
    for (int am = 0; am < 8; ++am) {
#pragma unroll
        for (int an = 0; an < 4; ++an) {
            const int col = n0 + wn * 64 + an * 16 + r;
            const int row0 = m0 + wm * 128 + am * 16 + q4 * 4;
            if (MODE == 0) {
#pragma unroll
                for (int i2 = 0; i2 < 4; ++i2)
                    ((u16*)C0)[(size_t)z * strC + (size_t)(row0 + i2) * ldc + col] =
                        f2bf(acc[am][an][i2] * alpha);
            } else if (MODE == 3) {
                const float bv = b0[col];
#pragma unroll
                for (int i2 = 0; i2 < 4; ++i2) {
                    const size_t idx = (size_t)(row0 + i2) * ldc + col;
                    ((float*)C0)[idx] = acc[am][an][i2] + bv + resid[idx];
                }
            } else {  // MODE 4: fused QKV
                const int seg = col >> 9, cl = col & 511;
                const float bv = (seg == 0 ? b0 : seg == 1 ? b1 : b2)[cl];
                if (seg < 2) {
                    u16* base = (u16*)C0 + (size_t)seg * (size_t)NM * 512;
#pragma unroll
                    for (int i2 = 0; i2 < 4; ++i2)
                        base[(size_t)(row0 + i2) * 512 + cl] = f2bf(acc[am][an][i2] + bv);
                } else {
                    const int bb = row0 >> 10, ml = row0 & 1023;
                    ushort4 o;
                    o.x = f2bf(acc[am][an][0] + bv);
                    o.y = f2bf(acc[am][an][1] + bv);
                    o.z = f2bf(acc[am][an][2] + bv);
                    o.w = f2bf(acc[am][an][3] + bv);
                    *(ushort4*)((u16*)C1 + ((size_t)(bb * 512 + cl)) * 1024 + ml) = o;
                }
            }
        }
    }
}

// ---------------------------------------------------------------- softmax (in place)
__global__ __launch_bounds__(256) void softmax_kernel(u16* __restrict__ s)
{
    const int wave = (blockIdx.x << 2) | (threadIdx.x >> 6);
    const int lane = threadIdx.x & 63;
    u16* rowp = s + (size_t)wave * 1024;

    float v[16];
#pragma unroll
    for (int c = 0; c < 4; ++c) {
        const ushort4 raw = *(const ushort4*)(rowp + c * 256 + lane * 4);
        v[c * 4 + 0] = bf2f(raw.x);
        v[c * 4 + 1] = bf2f(raw.y);
        v[c * 4 + 2] = bf2f(raw.z);
        v[c * 4 + 3] = bf2f(raw.w);
    }
    float m = -1e30f;
#pragma unroll
    for (int i = 0; i < 16; ++i) m = fmaxf(m, v[i]);
#pragma unroll
    for (int off = 32; off; off >>= 1) m = fmaxf(m, __shfl_xor(m, off));
    float sum = 0.f;
#pragma unroll
    for (int i = 0; i < 16; ++i) {
        v[i] = __expf(v[i] - m);
        sum += v[i];
    }
#pragma unroll
    for (int off = 32; off; off >>= 1) sum += __shfl_xor(sum, off);
    const float inv = 1.0f / sum;
#pragma unroll
    for (int c = 0; c < 4; ++c) {
        ushort4 o;
        o.x = f2bf(v[c * 4 + 0] * inv);
        o.y = f2bf(v[c * 4 + 1] * inv);
        o.z = f2bf(v[c * 4 + 2] * inv);
        o.w = f2bf(v[c * 4 + 3] * inv);
        *(ushort4*)(rowp + c * 256 + lane * 4) = o;
    }
}

// ---------------------------------------------------------------- launch
extern "C" void kernel_launch(void* const* d_in, const int* in_sizes, int n_in,
                              void* d_out, int out_size, void* d_ws, size_t ws_size,
                              hipStream_t stream)
{
    (void)in_sizes; (void)n_in; (void)out_size; (void)ws_size;
    const float* x   = (const float*)d_in[0];
    const float* nsc = (const float*)d_in[1];
    const float* nbi = (const float*)d_in[2];
    const float* wq  = (const float*)d_in[3];
    const float* bq  = (const float*)d_in[4];
    const float* wk  = (const float*)d_in[5];
    const float* bk  = (const float*)d_in[6];
    const float* wv  = (const float*)d_in[7];
    const float* bv  = (const float*)d_in[8];
    const float* wp  = (const float*)d_in[9];
    const float* bp  = (const float*)d_in[10];
    float* out = (float*)d_out;

    char* ws = (char*)d_ws;
    u16* qb = (u16*)(ws);                        // 32 MB  [32768,512]  (q)
    u16* kb = (u16*)(ws + (32ull << 20));        // 32 MB  [32768,512]  (k)
    u16* vT = (u16*)(ws + (64ull << 20));        // 32 MB  [32,512,1024]
    u16* sb = (u16*)(ws + (96ull << 20));        // 64 MB  [32,1024,1024] (scores)
    u16* hn = (u16*)(ws + (160ull << 20));       // 32 MB  [32768,512]
    u16* ao = hn;                                 // reuse: hn dead after QKV
    u16* wT = (u16*)(ws + (192ull << 20));       // 2 MB   [4*512,512] stacked q,k,v,p
    float2* gnp = (float2*)sb;                   // 64 KB partials (dead before scores)
    float2* gns = (float2*)(ws + (97ull << 20)); // 8 KB stats

    transpose_weights<<<4096, 256, 0, stream>>>(wq, wk, wv, wp, wT);
    gn_partial<<<256, 256, 0, stream>>>(x, gnp);
    gn_stats<<<4, 256, 0, stream>>>(gnp, gns);
    gn_apply<<<16384, 256, 0, stream>>>(x, gns, nsc, nbi, hn);

    const dim3 blk(512);
    // fused QKV: M=32768 (128 strips), N=1536 (6 blocks): 8 XCD * 16 * 6 = 768
    gemm8<4, 6><<<768, blk, 0, stream>>>(hn, wT, qb, vT, bq, bk, bv, nullptr,
                                         512, 512, 0, 0, 0, 1.f);

    const dim3 g2(4, 4, 32);                     // scores: N=1024, M=1024, 32 batches
    gemm8<0, 0><<<g2, blk, 0, stream>>>(qb, kb, sb, nullptr, nullptr, nullptr, nullptr, nullptr,
                                        512, 1024, 1024L * 512, 1024L * 512, 1024L * 1024,
                                        0.04419417382415922f);  // 512^-0.5
    softmax_kernel<<<8192, dim3(256), 0, stream>>>(sb);

    const dim3 g3(2, 4, 32);                     // out: N=512, M=1024, 32 batches
    gemm8<0, 0><<<g3, blk, 0, stream>>>(sb, vT, ao, nullptr, nullptr, nullptr, nullptr, nullptr,
                                        1024, 512, 1024L * 1024, 512L * 1024, 1024L * 512,
                                        1.f);

    // proj: M=32768 (128 strips), N=512 (2 blocks): 8 XCD * 16 * 2 = 256
    gemm8<3, 2><<<256, blk, 0, stream>>>(ao, wT + 3 * 262144, out, nullptr, bp, nullptr, nullptr, x,
                                         512, 512, 0, 0, 0, 1.f);
}

// Round 2
// 378.369 us; speedup vs baseline: 1.1372x; 1.0173x over previous
//
#include <hip/hip_runtime.h>
#include <stdint.h>
#include <stddef.h>

// AttnBlock: x[32,32,32,512] fp32 -> groupnorm(32) -> q/k/v 1x1 conv -> attn(seq=1024) -> proj -> +x
// R7: fix R6's pipeline kill. asm("s_barrier":::"memory") made SIInsertWaitcnts
// emit vmcnt(0) lgkmcnt(0) before EVERY barrier (16 drains/iter) -> degenerated
// to m233's drained 2-phase (~600 TF). Replace with __builtin_amdgcn_s_barrier()
// + clobber-free s_waitcnt asm + sched_barrier(0) pinning (rule 18 / m201 template).

typedef short bh8 __attribute__((ext_vector_type(8)));   // 8 bf16 payload (4 VGPRs)
typedef __bf16 bf8 __attribute__((ext_vector_type(8)));  // builtin operand type
typedef float f4 __attribute__((ext_vector_type(4)));
typedef unsigned short u16;

#define NB 32
#define HW 1024
#define NC 512
#define NM (NB * HW)   // 32768 rows total

__device__ __forceinline__ u16 f2bf(float f) {
    union { float f; uint32_t u; } v; v.f = f;
    uint32_t r = v.u + 0x7FFFu + ((v.u >> 16) & 1u);  // RNE
    return (u16)(r >> 16);
}
__device__ __forceinline__ float bf2f(u16 h) {
    union { uint32_t u; float f; } v; v.u = ((uint32_t)h) << 16;
    return v.f;
}

using gas_p = const __attribute__((address_space(1))) void*;
using las_p = __attribute__((address_space(3))) void*;

__device__ __forceinline__ void async16(const void* g, void* l) {
    __builtin_amdgcn_global_load_lds((gas_p)g, (las_p)l, 16, 0, 0);
}

__device__ __forceinline__ f4 mfma16(bh8 a, bh8 b, f4 c) {
    return __builtin_amdgcn_mfma_f32_16x16x32_bf16(
        __builtin_bit_cast(bf8, a), __builtin_bit_cast(bf8, b), c, 0, 0, 0);
}

// Template-correct sync primitives (m201): builtin barrier (no implicit drain),
// clobber-free waitcnt asm, sched_barrier(0) to pin against scheduler motion.
#define BAR()    __builtin_amdgcn_s_barrier()
#define SBAR()   __builtin_amdgcn_sched_barrier(0)
#define VMCNT(N) asm volatile("s_waitcnt vmcnt(" #N ")")
#define LGKM0()  asm volatile("s_waitcnt lgkmcnt(0)")

// ---------------------------------------------------------------- transpose weights
__global__ __launch_bounds__(256) void transpose_weights(
    const float* __restrict__ wq, const float* __restrict__ wk,
    const float* __restrict__ wv, const float* __restrict__ wp,
    u16* __restrict__ wT)
{
    int idx = blockIdx.x * 256 + threadIdx.x;      // 0 .. 4*512*512-1
    int m = idx >> 18;
    int r = idx & 0x3FFFF;                          // r = k*512 + n (coalesced read)
    int k = r >> 9, n = r & 511;
    const float* w = (m == 0) ? wq : (m == 1) ? wk : (m == 2) ? wv : wp;
    wT[((size_t)m << 18) + (size_t)n * 512 + k] = f2bf(w[r]);
}

// ---------------------------------------------------------------- group norm (3 stages)
__global__ __launch_bounds__(256) void gn_partial(
    const float* __restrict__ x, float2* __restrict__ part)
{
    const int b = blockIdx.x >> 3, s = blockIdx.x & 7;
    const int t = threadIdx.x;
    const int c0 = (t & 127) * 4;
    const int pr = t >> 7;
    const float* xb = x + (size_t)b * HW * NC + (size_t)(s * 128) * NC + c0;
    float sum = 0.f, sq = 0.f;
#pragma unroll 8
    for (int i = 0; i < 64; ++i) {
        const float4 v = *(const float4*)(xb + (size_t)(pr + i * 2) * NC);
        sum += v.x + v.y + v.z + v.w;
        sq  += v.x * v.x + v.y * v.y + v.z * v.z + v.w * v.w;
    }
    __shared__ float2 red[256];
    red[t] = make_float2(sum, sq);
    __syncthreads();
    if (t < 32) {
        float S = 0.f, Q = 0.f;
#pragma unroll
        for (int p = 0; p < 2; ++p)
#pragma unroll
            for (int j = 0; j < 4; ++j) {
                const float2 v = red[t * 4 + j + p * 128];
                S += v.x; Q += v.y;
            }
        part[(size_t)blockIdx.x * 32 + t] = make_float2(S, Q);
    }
}

__global__ __launch_bounds__(256) void gn_stats(
    const float2* __restrict__ part, float2* __restrict__ stats)
{
    const int p = blockIdx.x * 256 + threadIdx.x;   // 0..1023
    const int b = p >> 5, g = p & 31;
    float S = 0.f, Q = 0.f;
#pragma unroll
    for (int s = 0; s < 8; ++s) {
        const float2 v = part[((size_t)(b * 8 + s)) * 32 + g];
        S += v.x; Q += v.y;
    }
    const float mean = S * (1.f / 16384.f);
    const float var = Q * (1.f / 16384.f) - mean * mean;
    stats[p] = make_float2(mean, rsqrtf(var + 1e-6f));
}

__global__ __launch_bounds__(256) void gn_apply(
    const float* __restrict__ x, const float2* __restrict__ stats,
    const float* __restrict__ scale, const float* __restrict__ bias,
    u16* __restrict__ hn)
{
    const size_t idx = (size_t)blockIdx.x * 256 + threadIdx.x;  // float4 index
    const size_t e = idx * 4;
    const int c0 = (int)(e & 511);
    const int bg = (int)(e >> 19) * 32 + (c0 >> 4);
    const float2 st = stats[bg];
    const float4 v = *(const float4*)(x + e);
    const float4 sc = *(const float4*)(scale + c0);
    const float4 bi = *(const float4*)(bias + c0);
    ushort4 o;
    o.x = f2bf((v.x - st.x) * st.y * sc.x + bi.x);
    o.y = f2bf((v.y - st.x) * st.y * sc.y + bi.y);
    o.z = f2bf((v.z - st.x) * st.y * sc.z + bi.z);
    o.w = f2bf((v.w - st.x) * st.y * sc.w + bi.w);
    *(ushort4*)(hn + e) = o;
}

// ---------------------------------------------------------------- 8-phase 256x256 GEMM
// C[M,N] = A[M,K] * Bt[N,K]^T, bf16 in, fp32 accum. BM=BN=256, BK=64.
// 512 threads = 8 waves (2M x 4N); per wave 128x64 output = 8x4 16x16 frags.
// LDS: 2 K-tile buffers x (A[256][64] + B[256][64]) bf16 = 128 KiB.
// Swizzle: 16B-chunk c at row stored at phys chunk c ^ (row&7); staged via
// pre-swizzled GLOBAL source (global_load_lds dest is linear), read with XOR.
// Schedule: per iteration 2 K-tiles, 8 phases (gray-coded C quadrants);
// each phase stages one 16KB region whose last read was >=2 barriers ago;
// counted vmcnt(4) at phases 4 & 8 (never 0 except final-iter boundary).
//
// Region staging map (steady state, iter it; kt = 2*it):
//  p0: buf1.Aq1 <- kt+1   p1: buf1.Bq0 <- kt+1   (complete current buf1 tile)
//  p2: buf0.Aq0 <- kt+2   p3: buf0.Bq1 <- kt+2   [guard it<NI-1]
//  p4: buf0.Aq1 <- kt+2   p5: buf0.Bq0 <- kt+2   [guard]
//  p6: buf1.Aq0 <- kt+3   p7: buf1.Bq1 <- kt+3   [guard]
// Reads: p0..p3 = buf0 quadrants (0,0),(0,1),(1,1),(1,0); p4..p7 same on buf1.
// vmcnt ledger (2 loads/wave/phase): p3's VMCNT(4) completes prev{p6,p7}+p0,p1
// -> buf1 ready before p4; p7's VMCNT(4) completes p2..p5 -> buf0 ready for
// next iter's p0. Last iter: p2-p7 stage nothing -> p3 must VMCNT(0).

template <int MAT, int Q>
__device__ __forceinline__ void stage_region(u16* ldsmat, const u16* g, int ldG,
                                             int w, int lane) {
#pragma unroll
    for (int j = 0; j < 2; ++j) {
        const int rowbase = (MAT == 0)
            ? (j * 128 + Q * 64 + w * 8)
            : ((j * 2 + (w >> 2)) * 64 + Q * 32 + (w & 3) * 8);
        const int row = rowbase + (lane >> 3);
        const int c16 = (lane & 7) ^ (lane >> 3);       // inverse swizzle on source
        async16(g + (size_t)row * ldG + (c16 << 3), ldsmat + rowbase * 64);
    }
}

#define PHASE(P, D, QM, QN, SD, SMAT, SQ, SKT, GRD)                                \
    {                                                                              \
        bh8 paf[4][2], pbf[2][2];                                                  \
        _Pragma("unroll") for (int mt = 0; mt < 4; ++mt) {                         \
            const int arow = wm * 128 + (QM) * 64 + mt * 16 + r;                   \
            _Pragma("unroll") for (int kk = 0; kk < 2; ++kk)                       \
                paf[mt][kk] = *(const bh8*)&lds[D][0][arow * 64 +                  \
                    (((kk * 4 + q4) ^ (r & 7)) << 3)];                             \
        }                                                                          \
        _Pragma("unroll") for (int nt = 0; nt < 2; ++nt) {                         \
            const int brow = wn * 64 + (QN) * 32 + nt * 16 + r;                    \
            _Pragma("unroll") for (int kk = 0; kk < 2; ++kk)                       \
                pbf[nt][kk] = *(const bh8*)&lds[D][1][brow * 64 +                  \
                    (((kk * 4 + q4) ^ (r & 7)) << 3)];                             \
        }                                                                          \
        if (!(GRD) || it < NI - 1) {                                               \
            const size_t ko = (size_t)(2 * it + (SKT)) << 6;                       \
            if ((SMAT) == 0) stage_region<0, SQ>(&lds[SD][0][0], A_ + ko, K, wid, lane); \
            else             stage_region<1, SQ>(&lds[SD][1][0], B_ + ko, K, wid, lane); \
        }                                                                          \
        SBAR();                                                                    \
        BAR();                                                                     \
        LGKM0();                                                                   \
        SBAR();                                                                    \
        __builtin_amdgcn_s_setprio(1);                                             \
        _Pragma("unroll") for (int mt = 0; mt < 4; ++mt)                           \
            _Pragma("unroll") for (int nt = 0; nt < 2; ++nt)                       \
                _Pragma("unroll") for (int kk = 0; kk < 2; ++kk)                   \
                    acc[(QM) * 4 + mt][(QN) * 2 + nt] =                            \
                        mfma16(paf[mt][kk], pbf[nt][kk],                           \
                               acc[(QM) * 4 + mt][(QN) * 2 + nt]);                 \
        __builtin_amdgcn_s_setprio(0);                                             \
        SBAR();                                                                    \
        if ((P) == 3) { if (it < NI - 1) { VMCNT(4); } else { VMCNT(0); } SBAR(); }\
        if ((P) == 7) { VMCNT(4); SBAR(); }                                        \
        BAR();                                                                     \
    }

// MODE 0: bf16 C0 = alpha*acc (batched via blockIdx.z)
// MODE 3: fp32 C0 = acc + b0[col] + resid[row*ldc+col]
// MODE 4: fused QKV: col<1024 -> q/k (seg-strided); col>=1024 -> vT transposed
// SWZ > 0: 1D grid of 8*mper*SWZ blocks; xcd = bid&7; same mapping as before.
template <int MODE, int SWZ>
__global__ __launch_bounds__(512, 2) void gemm8(
    const u16* __restrict__ A, const u16* __restrict__ Bt,
    void* __restrict__ C0, void* __restrict__ C1,
    const float* __restrict__ b0, const float* __restrict__ b1,
    const float* __restrict__ b2, const float* __restrict__ resid,
    int K, int ldc, long strA, long strB, long strC, float alpha)
{
    __shared__ __align__(16) u16 lds[2][2][256 * 64];   // 128 KiB
    const int tid = threadIdx.x;
    const int wid = tid >> 6, lane = tid & 63;
    const int wm = wid >> 2, wn = wid & 3;              // 2 x 4 wave grid
    const int r = lane & 15, q4 = lane >> 4;
    const int z = blockIdx.z;

    int m0, n0;
    if (SWZ > 0) {
        const int g = blockIdx.x;
        const int xcd = g & 7, s = g >> 3;
        const int mper = (int)(gridDim.x >> 3) / SWZ;
        m0 = (xcd * mper + s / SWZ) * 256;
        n0 = (s % SWZ) * 256;
    } else {
        m0 = blockIdx.y * 256;
        n0 = blockIdx.x * 256;
    }

    const u16* A_ = A + (size_t)z * strA + (size_t)m0 * K;
    const u16* B_ = Bt + (size_t)z * strB + (size_t)n0 * K;

    f4 acc[8][4];
#pragma unroll
    for (int ii = 0; ii < 8; ++ii)
#pragma unroll
        for (int jj = 0; jj < 4; ++jj) {
            f4 zr = {0.f, 0.f, 0.f, 0.f};
            acc[ii][jj] = zr;
        }

    const int NI = K >> 7;   // 2 K-tiles (of 64) per iteration; K in {512,1024}

    // prologue: issue order == steady-state p2..p7 (vmcnt counting relies on it)
    stage_region<0, 0>(&lds[0][0][0], A_,      K, wid, lane);  // buf0.Aq0 kt0
    stage_region<1, 1>(&lds[0][1][0], B_,      K, wid, lane);  // buf0.Bq1 kt0
    stage_region<0, 1>(&lds[0][0][0], A_,      K, wid, lane);  // buf0.Aq1 kt0
    stage_region<1, 0>(&lds[0][1][0], B_,      K, wid, lane);  // buf0.Bq0 kt0
    stage_region<0, 0>(&lds[1][0][0], A_ + 64, K, wid, lane);  // buf1.Aq0 kt1
    stage_region<1, 1>(&lds[1][1][0], B_ + 64, K, wid, lane);  // buf1.Bq1 kt1
    VMCNT(4);   // buf0 fully landed; buf1.Aq0/Bq1 may remain in flight
    SBAR();
    BAR();

    for (int it = 0; it < NI; ++it) {
        PHASE(0, 0, 0, 0, 1, 0, 1, 1, 0)
        PHASE(1, 0, 0, 1, 1, 1, 0, 1, 0)
        PHASE(2, 0, 1, 1, 0, 0, 0, 2, 1)
        PHASE(3, 0, 1, 0, 0, 1, 1, 2, 1)
        PHASE(4, 1, 0, 0, 0, 0, 1, 2, 1)
        PHASE(5, 1, 0, 1, 0, 1, 0, 2, 1)
        PHASE(6, 1, 1, 1, 1, 0, 0, 3, 1)
        PHASE(7, 1, 1, 0, 1, 1, 1, 3, 1)
    }

    // epilogue: C/D layout col = lane&15, row = (lane>>4)*4 + i
#pragma unroll
    for (int am = 0; am < 8; ++am) {
#pragma unroll
        for (int an = 0; an < 4; ++an) {
            const int col = n0 + wn * 64 + an * 16 + r;
            const int row0 = m0 + wm * 128 + am * 16 + q4 * 4;
            if (MODE == 0) {
#pragma unroll
                for (int i2 = 0; i2 < 4; ++i2)
                    ((u16*)C0)[(size_t)z * strC + (size_t)(row0 + i2) * ldc + col] =
                        f2bf(acc[am][an][i2] * alpha);
            } else if (MODE == 3) {
                const float bv = b0[col];
#pragma unroll
                for (int i2 = 0; i2 < 4; ++i2) {
                    const size_t idx = (size_t)(row0 + i2) * ldc + col;
                    ((float*)C0)[idx] = acc[am][an][i2] + bv + resid[idx];
                }
            } else {  // MODE 4: fused QKV
                const int seg = col >> 9, cl = col & 511;
                const float bv = (seg == 0 ? b0 : seg == 1 ? b1 : b2)[cl];
                if (seg < 2) {
                    u16* base = (u16*)C0 + (size_t)seg * (size_t)NM * 512;
#pragma unroll
                    for (int i2 = 0; i2 < 4; ++i2)
                        base[(size_t)(row0 + i2) * 512 + cl] = f2bf(acc[am][an][i2] + bv);
                } else {
                    const int bb = row0 >> 10, ml = row0 & 1023;
                    ushort4 o;
                    o.x = f2bf(acc[am][an][0] + bv);
                    o.y = f2bf(acc[am][an][1] + bv);
                    o.z = f2bf(acc[am][an][2] + bv);
                    o.w = f2bf(acc[am][an][3] + bv);
                    *(ushort4*)((u16*)C1 + ((size_t)(bb * 512 + cl)) * 1024 + ml) = o;
                }
            }
        }
    }
}

// ---------------------------------------------------------------- softmax (in place)
__global__ __launch_bounds__(256) void softmax_kernel(u16* __restrict__ s)
{
    const int wave = (blockIdx.x << 2) | (threadIdx.x >> 6);
    const int lane = threadIdx.x & 63;
    u16* rowp = s + (size_t)wave * 1024;

    float v[16];
#pragma unroll
    for (int c = 0; c < 4; ++c) {
        const ushort4 raw = *(const ushort4*)(rowp + c * 256 + lane * 4);
        v[c * 4 + 0] = bf2f(raw.x);
        v[c * 4 + 1] = bf2f(raw.y);
        v[c * 4 + 2] = bf2f(raw.z);
        v[c * 4 + 3] = bf2f(raw.w);
    }
    float m = -1e30f;
#pragma unroll
    for (int i = 0; i < 16; ++i) m = fmaxf(m, v[i]);
#pragma unroll
    for (int off = 32; off; off >>= 1) m = fmaxf(m, __shfl_xor(m, off));
    float sum = 0.f;
#pragma unroll
    for (int i = 0; i < 16; ++i) {
        v[i] = __expf(v[i] - m);
        sum += v[i];
    }
#pragma unroll
    for (int off = 32; off; off >>= 1) sum += __shfl_xor(sum, off);
    const float inv = 1.0f / sum;
#pragma unroll
    for (int c = 0; c < 4; ++c) {
        ushort4 o;
        o.x = f2bf(v[c * 4 + 0] * inv);
        o.y = f2bf(v[c * 4 + 1] * inv);
        o.z = f2bf(v[c * 4 + 2] * inv);
        o.w = f2bf(v[c * 4 + 3] * inv);
        *(ushort4*)(rowp + c * 256 + lane * 4) = o;
    }
}

// ---------------------------------------------------------------- launch
extern "C" void kernel_launch(void* const* d_in, const int* in_sizes, int n_in,
                              void* d_out, int out_size, void* d_ws, size_t ws_size,
                              hipStream_t stream)
{
    (void)in_sizes; (void)n_in; (void)out_size; (void)ws_size;
    const float* x   = (const float*)d_in[0];
    const float* nsc = (const float*)d_in[1];
    const float* nbi = (const float*)d_in[2];
    const float* wq  = (const float*)d_in[3];
    const float* bq  = (const float*)d_in[4];
    const float* wk  = (const float*)d_in[5];
    const float* bk  = (const float*)d_in[6];
    const float* wv  = (const float*)d_in[7];
    const float* bv  = (const float*)d_in[8];
    const float* wp  = (const float*)d_in[9];
    const float* bp  = (const float*)d_in[10];
    float* out = (float*)d_out;

    char* ws = (char*)d_ws;
    u16* qb = (u16*)(ws);                        // 32 MB  [32768,512]  (q)
    u16* kb = (u16*)(ws + (32ull << 20));        // 32 MB  [32768,512]  (k)
    u16* vT = (u16*)(ws + (64ull << 20));        // 32 MB  [32,512,1024]
    u16* sb = (u16*)(ws + (96ull << 20));        // 64 MB  [32,1024,1024] (scores)
    u16* hn = (u16*)(ws + (160ull << 20));       // 32 MB  [32768,512]
    u16* ao = hn;                                 // reuse: hn dead after QKV
    u16* wT = (u16*)(ws + (192ull << 20));       // 2 MB   [4*512,512] stacked q,k,v,p
    float2* gnp = (float2*)sb;                   // 64 KB partials (dead before scores)
    float2* gns = (float2*)(ws + (97ull << 20)); // 8 KB stats

    transpose_weights<<<4096, 256, 0, stream>>>(wq, wk, wv, wp, wT);
    gn_partial<<<256, 256, 0, stream>>>(x, gnp);
    gn_stats<<<4, 256, 0, stream>>>(gnp, gns);
    gn_apply<<<16384, 256, 0, stream>>>(x, gns, nsc, nbi, hn);

    const dim3 blk(512);
    // fused QKV: M=32768 (128 strips), N=1536 (6 blocks): 8 XCD * 16 * 6 = 768
    gemm8<4, 6><<<768, blk, 0, stream>>>(hn, wT, qb, vT, bq, bk, bv, nullptr,
                                         512, 512, 0, 0, 0, 1.f);

    const dim3 g2(4, 4, 32);                     // scores: N=1024, M=1024, 32 batches
    gemm8<0, 0><<<g2, blk, 0, stream>>>(qb, kb, sb, nullptr, nullptr, nullptr, nullptr, nullptr,
                                        512, 1024, 1024L * 512, 1024L * 512, 1024L * 1024,
                                        0.04419417382415922f);  // 512^-0.5
    softmax_kernel<<<8192, dim3(256), 0, stream>>>(sb);

    const dim3 g3(2, 4, 32);                     // out: N=512, M=1024, 32 batches
    gemm8<0, 0><<<g3, blk, 0, stream>>>(sb, vT, ao, nullptr, nullptr, nullptr, nullptr, nullptr,
                                        1024, 512, 1024L * 1024, 512L * 1024, 1024L * 512,
                                        1.f);

    // proj: M=32768 (128 strips), N=512 (2 blocks): 8 XCD * 16 * 2 = 256
    gemm8<3, 2><<<256, blk, 0, stream>>>(ao, wT + 3 * 262144, out, nullptr, bp, nullptr, nullptr, x,
                                         512, 512, 0, 0, 0, 1.f);
}

// Round 3
// 377.913 us; speedup vs baseline: 1.1386x; 1.0012x over previous
//
#include <hip/hip_runtime.h>
#include <stdint.h>
#include <stddef.h>

// AttnBlock: x[32,32,32,512] fp32 -> groupnorm(32) -> q/k/v 1x1 conv -> attn(seq=1024) -> proj -> +x
// R8: two fixes to the 8-phase GEMM.
//  (1) Gray-code fragment REUSE: A-frags persist when QM unchanged, B-frags when
//      QN unchanged -> avg 7 ds_read_b128/phase instead of 12. R6/R7 were
//      LDS-read-bound (12 reads x 8 waves x 12cy = 1152cy/phase vs 620cy MFMA).
//  (2) Minimal sync: builtin s_barrier (no clobber -> no auto vmcnt(0) drain,
//      R6's bug), clobber-free counted VMCNT asm, only one sched_barrier(0)
//      after each VMCNT (R7's 5-per-phase pinning was m141's regression).

typedef short bh8 __attribute__((ext_vector_type(8)));   // 8 bf16 payload (4 VGPRs)
typedef __bf16 bf8 __attribute__((ext_vector_type(8)));  // builtin operand type
typedef float f4 __attribute__((ext_vector_type(4)));
typedef unsigned short u16;

#define NB 32
#define HW 1024
#define NC 512
#define NM (NB * HW)   // 32768 rows total

__device__ __forceinline__ u16 f2bf(float f) {
    union { float f; uint32_t u; } v; v.f = f;
    uint32_t r = v.u + 0x7FFFu + ((v.u >> 16) & 1u);  // RNE
    return (u16)(r >> 16);
}
__device__ __forceinline__ float bf2f(u16 h) {
    union { uint32_t u; float f; } v; v.u = ((uint32_t)h) << 16;
    return v.f;
}

using gas_p = const __attribute__((address_space(1))) void*;
using las_p = __attribute__((address_space(3))) void*;

__device__ __forceinline__ void async16(const void* g, void* l) {
    __builtin_amdgcn_global_load_lds((gas_p)g, (las_p)l, 16, 0, 0);
}

__device__ __forceinline__ f4 mfma16(bh8 a, bh8 b, f4 c) {
    return __builtin_amdgcn_mfma_f32_16x16x32_bf16(
        __builtin_bit_cast(bf8, a), __builtin_bit_cast(bf8, b), c, 0, 0, 0);
}

#define BAR()    __builtin_amdgcn_s_barrier()
#define SBAR()   __builtin_amdgcn_sched_barrier(0)
#define VMCNT(N) asm volatile("s_waitcnt vmcnt(" #N ")")

// ---------------------------------------------------------------- transpose weights
__global__ __launch_bounds__(256) void transpose_weights(
    const float* __restrict__ wq, const float* __restrict__ wk,
    const float* __restrict__ wv, const float* __restrict__ wp,
    u16* __restrict__ wT)
{
    int idx = blockIdx.x * 256 + threadIdx.x;      // 0 .. 4*512*512-1
    int m = idx >> 18;
    int r = idx & 0x3FFFF;                          // r = k*512 + n (coalesced read)
    int k = r >> 9, n = r & 511;
    const float* w = (m == 0) ? wq : (m == 1) ? wk : (m == 2) ? wv : wp;
    wT[((size_t)m << 18) + (size_t)n * 512 + k] = f2bf(w[r]);
}

// ---------------------------------------------------------------- group norm (3 stages)
__global__ __launch_bounds__(256) void gn_partial(
    const float* __restrict__ x, float2* __restrict__ part)
{
    const int b = blockIdx.x >> 3, s = blockIdx.x & 7;
    const int t = threadIdx.x;
    const int c0 = (t & 127) * 4;
    const int pr = t >> 7;
    const float* xb = x + (size_t)b * HW * NC + (size_t)(s * 128) * NC + c0;
    float sum = 0.f, sq = 0.f;
#pragma unroll 8
    for (int i = 0; i < 64; ++i) {
        const float4 v = *(const float4*)(xb + (size_t)(pr + i * 2) * NC);
        sum += v.x + v.y + v.z + v.w;
        sq  += v.x * v.x + v.y * v.y + v.z * v.z + v.w * v.w;
    }
    __shared__ float2 red[256];
    red[t] = make_float2(sum, sq);
    __syncthreads();
    if (t < 32) {
        float S = 0.f, Q = 0.f;
#pragma unroll
        for (int p = 0; p < 2; ++p)
#pragma unroll
            for (int j = 0; j < 4; ++j) {
                const float2 v = red[t * 4 + j + p * 128];
                S += v.x; Q += v.y;
            }
        part[(size_t)blockIdx.x * 32 + t] = make_float2(S, Q);
    }
}

__global__ __launch_bounds__(256) void gn_stats(
    const float2* __restrict__ part, float2* __restrict__ stats)
{
    const int p = blockIdx.x * 256 + threadIdx.x;   // 0..1023
    const int b = p >> 5, g = p & 31;
    float S = 0.f, Q = 0.f;
#pragma unroll
    for (int s = 0; s < 8; ++s) {
        const float2 v = part[((size_t)(b * 8 + s)) * 32 + g];
        S += v.x; Q += v.y;
    }
    const float mean = S * (1.f / 16384.f);
    const float var = Q * (1.f / 16384.f) - mean * mean;
    stats[p] = make_float2(mean, rsqrtf(var + 1e-6f));
}

__global__ __launch_bounds__(256) void gn_apply(
    const float* __restrict__ x, const float2* __restrict__ stats,
    const float* __restrict__ scale, const float* __restrict__ bias,
    u16* __restrict__ hn)
{
    const size_t idx = (size_t)blockIdx.x * 256 + threadIdx.x;  // float4 index
    const size_t e = idx * 4;
    const int c0 = (int)(e & 511);
    const int bg = (int)(e >> 19) * 32 + (c0 >> 4);
    const float2 st = stats[bg];
    const float4 v = *(const float4*)(x + e);
    const float4 sc = *(const float4*)(scale + c0);
    const float4 bi = *(const float4*)(bias + c0);
    ushort4 o;
    o.x = f2bf((v.x - st.x) * st.y * sc.x + bi.x);
    o.y = f2bf((v.y - st.x) * st.y * sc.y + bi.y);
    o.z = f2bf((v.z - st.x) * st.y * sc.z + bi.z);
    o.w = f2bf((v.w - st.x) * st.y * sc.w + bi.w);
    *(ushort4*)(hn + e) = o;
}

// ---------------------------------------------------------------- 8-phase 256x256 GEMM
// C[M,N] = A[M,K] * Bt[N,K]^T, bf16 in, fp32 accum. BM=BN=256, BK=64.
// 512 threads = 8 waves (2M x 4N); per wave 128x64 output = 8x4 16x16 frags.
// LDS: 2 K-tile buffers x (A[256][64] + B[256][64]) bf16 = 128 KiB.
// Swizzle: 16B-chunk c at row stored at phys chunk c ^ (row&7); staged via
// pre-swizzled GLOBAL source (global_load_lds dest is linear), read with XOR.
//
// Phase table (gray-coded quadrants; LA/LB = load A/B frags from LDS this phase):
//  P  buf QM QN LA LB | stages (region <- K-tile)
//  0   0   0  0  1  1 | buf1.Aq1 <- kt+1
//  1   0   0  1  0  1 | buf1.Bq0 <- kt+1
//  2   0   1  1  1  0 | buf0.Aq0 <- kt+2  [it<NI-1]
//  3   0   1  0  0  1 | buf0.Bq1 <- kt+2  [g]  VMCNT(4|0)
//  4   1   0  0  1  1 | buf0.Aq1 <- kt+2  [g]
//  5   1   0  1  0  1 | buf0.Bq0 <- kt+2  [g]
//  6   1   1  1  1  0 | buf1.Aq0 <- kt+3  [g]
//  7   1   1  0  0  1 | buf1.Bq1 <- kt+3  [g]  VMCNT(4)
// vmcnt ledger (2 loads/wave/stage): p3's VMCNT(4) leaves p2,p3 in flight ->
// prev{p6,p7}+p0,p1 landed -> buf1(kt+1) ready before p4 reads it. p7's
// VMCNT(4) leaves p6,p7 -> p2..p5 landed -> buf0(kt+2) ready for next p0.
// Each staged region's last ds_read precedes the stage by >=1 full barrier.

template <int MAT, int Q>
__device__ __forceinline__ void stage_region(u16* ldsmat, const u16* g, int ldG,
                                             int w, int lane) {
#pragma unroll
    for (int j = 0; j < 2; ++j) {
        const int rowbase = (MAT == 0)
            ? (j * 128 + Q * 64 + w * 8)
            : ((j * 2 + (w >> 2)) * 64 + Q * 32 + (w & 3) * 8);
        const int row = rowbase + (lane >> 3);
        const int c16 = (lane & 7) ^ (lane >> 3);       // inverse swizzle on source
        async16(g + (size_t)row * ldG + (c16 << 3), ldsmat + rowbase * 64);
    }
}

#define PHASE(P, D, QM, QN, LA, LB, SD, SMAT, SQ, SKT, GRD)                        \
    {                                                                              \
        if (LA) {                                                                  \
            _Pragma("unroll") for (int mt = 0; mt < 4; ++mt) {                     \
                const int arow = wm * 128 + (QM) * 64 + mt * 16 + r;               \
                _Pragma("unroll") for (int kk = 0; kk < 2; ++kk)                   \
                    paf[mt][kk] = *(const bh8*)&lds[D][0][arow * 64 +              \
                        (((kk * 4 + q4) ^ (r & 7)) << 3)];                         \
            }                                                                      \
        }                                                                          \
        if (LB) {                                                                  \
            _Pragma("unroll") for (int nt = 0; nt < 2; ++nt) {                     \
                const int brow = wn * 64 + (QN) * 32 + nt * 16 + r;                \
                _Pragma("unroll") for (int kk = 0; kk < 2; ++kk)                   \
                    pbf[nt][kk] = *(const bh8*)&lds[D][1][brow * 64 +              \
                        (((kk * 4 + q4) ^ (r & 7)) << 3)];                         \
            }                                                                      \
        }                                                                          \
        if (!(GRD) || it < NI - 1) {                                               \
            const size_t ko = (size_t)(2 * it + (SKT)) << 6;                       \
            if ((SMAT) == 0) stage_region<0, SQ>(&lds[SD][0][0], A_ + ko, K, wid, lane); \
            else             stage_region<1, SQ>(&lds[SD][1][0], B_ + ko, K, wid, lane); \
        }                                                                          \
        BAR();                                                                     \
        __builtin_amdgcn_s_setprio(1);                                             \
        _Pragma("unroll") for (int mt = 0; mt < 4; ++mt)                           \
            _Pragma("unroll") for (int nt = 0; nt < 2; ++nt)                       \
                _Pragma("unroll") for (int kk = 0; kk < 2; ++kk)                   \
                    acc[(QM) * 4 + mt][(QN) * 2 + nt] =                            \
                        mfma16(paf[mt][kk], pbf[nt][kk],                           \
                               acc[(QM) * 4 + mt][(QN) * 2 + nt]);                 \
        __builtin_amdgcn_s_setprio(0);                                             \
        if ((P) == 3) { if (it < NI - 1) { VMCNT(4); } else { VMCNT(0); } SBAR(); }\
        if ((P) == 7) { VMCNT(4); SBAR(); }                                        \
        BAR();                                                                     \
    }

// MODE 0: bf16 C0 = alpha*acc (batched via blockIdx.z)
// MODE 3: fp32 C0 = acc + b0[col] + resid[row*ldc+col]
// MODE 4: fused QKV: col<1024 -> q/k (seg-strided); col>=1024 -> vT transposed
// SWZ > 0: 1D grid of 8*mper*SWZ blocks; xcd = bid&7; same mapping as before.
template <int MODE, int SWZ>
__global__ __launch_bounds__(512, 2) void gemm8(
    const u16* __restrict__ A, const u16* __restrict__ Bt,
    void* __restrict__ C0, void* __restrict__ C1,
    const float* __restrict__ b0, const float* __restrict__ b1,
    const float* __restrict__ b2, const float* __restrict__ resid,
    int K, int ldc, long strA, long strB, long strC, float alpha)
{
    __shared__ __align__(16) u16 lds[2][2][256 * 64];   // 128 KiB
    const int tid = threadIdx.x;
    const int wid = tid >> 6, lane = tid & 63;
    const int wm = wid >> 2, wn = wid & 3;              // 2 x 4 wave grid
    const int r = lane & 15, q4 = lane >> 4;
    const int z = blockIdx.z;

    int m0, n0;
    if (SWZ > 0) {
        const int g = blockIdx.x;
        const int xcd = g & 7, s = g >> 3;
        const int mper = (int)(gridDim.x >> 3) / SWZ;
        m0 = (xcd * mper + s / SWZ) * 256;
        n0 = (s % SWZ) * 256;
    } else {
        m0 = blockIdx.y * 256;
        n0 = blockIdx.x * 256;
    }

    const u16* A_ = A + (size_t)z * strA + (size_t)m0 * K;
    const u16* B_ = Bt + (size_t)z * strB + (size_t)n0 * K;

    f4 acc[8][4];
#pragma unroll
    for (int ii = 0; ii < 8; ++ii)
#pragma unroll
        for (int jj = 0; jj < 4; ++jj) {
            f4 zr = {0.f, 0.f, 0.f, 0.f};
            acc[ii][jj] = zr;
        }
    bh8 paf[4][2], pbf[2][2];                            // persistent fragments

    const int NI = K >> 7;   // 2 K-tiles (of 64) per iteration; K in {512,1024}

    // prologue: issue order == steady-state p2..p7 (vmcnt counting relies on it)
    stage_region<0, 0>(&lds[0][0][0], A_,      K, wid, lane);  // buf0.Aq0 kt0
    stage_region<1, 1>(&lds[0][1][0], B_,      K, wid, lane);  // buf0.Bq1 kt0
    stage_region<0, 1>(&lds[0][0][0], A_,      K, wid, lane);  // buf0.Aq1 kt0
    stage_region<1, 0>(&lds[0][1][0], B_,      K, wid, lane);  // buf0.Bq0 kt0
    stage_region<0, 0>(&lds[1][0][0], A_ + 64, K, wid, lane);  // buf1.Aq0 kt1
    stage_region<1, 1>(&lds[1][1][0], B_ + 64, K, wid, lane);  // buf1.Bq1 kt1
    VMCNT(4);   // buf0 fully landed; buf1.Aq0/Bq1 may remain in flight
    SBAR();
    BAR();

    for (int it = 0; it < NI; ++it) {
        PHASE(0, 0, 0, 0, 1, 1, 1, 0, 1, 1, 0)
        PHASE(1, 0, 0, 1, 0, 1, 1, 1, 0, 1, 0)
        PHASE(2, 0, 1, 1, 1, 0, 0, 0, 0, 2, 1)
        PHASE(3, 0, 1, 0, 0, 1, 0, 1, 1, 2, 1)
        PHASE(4, 1, 0, 0, 1, 1, 0, 0, 1, 2, 1)
        PHASE(5, 1, 0, 1, 0, 1, 0, 1, 0, 2, 1)
        PHASE(6, 1, 1, 1, 1, 0, 1, 0, 0, 3, 1)
        PHASE(7, 1, 1, 0, 0, 1, 1, 1, 1, 3, 1)
    }

    // epilogue: C/D layout col = lane&15, row = (lane>>4)*4 + i
#pragma unroll
    for (int am = 0; am < 8; ++am) {
#pragma unroll
        for (int an = 0; an < 4; ++an) {
            const int col = n0 + wn * 64 + an * 16 + r;
            const int row0 = m0 + wm * 128 + am * 16 + q4 * 4;
            if (MODE == 0) {
#pragma unroll
                for (int i2 = 0; i2 < 4; ++i2)
                    ((u16*)C0)[(size_t)z * strC + (size_t)(row0 + i2) * ldc + col] =
                        f2bf(acc[am][an][i2] * alpha);
            } else if (MODE == 3) {
                const float bv = b0[col];
#pragma unroll
                for (int i2 = 0; i2 < 4; ++i2) {
                    const size_t idx = (size_t)(row0 + i2) * ldc + col;
                    ((float*)C0)[idx] = acc[am][an][i2] + bv + resid[idx];
                }
            } else {  // MODE 4: fused QKV
                const int seg = col >> 9, cl = col & 511;
                const float bv = (seg == 0 ? b0 : seg == 1 ? b1 : b2)[cl];
                if (seg < 2) {
                    u16* base = (u16*)C0 + (size_t)seg * (size_t)NM * 512;
#pragma unroll
                    for (int i2 = 0; i2 < 4; ++i2)
                        base[(size_t)(row0 + i2) * 512 + cl] = f2bf(acc[am][an][i2] + bv);
                } else {
                    const int bb = row0 >> 10, ml = row0 & 1023;
                    ushort4 o;
                    o.x = f2bf(acc[am][an][0] + bv);
                    o.y = f2bf(acc[am][an][1] + bv);
                    o.z = f2bf(acc[am][an][2] + bv);
                    o.w = f2bf(acc[am][an][3] + bv);
                    *(ushort4*)((u16*)C1 + ((size_t)(bb * 512 + cl)) * 1024 + ml) = o;
                }
            }
        }
    }
}

// ---------------------------------------------------------------- softmax (in place)
__global__ __launch_bounds__(256) void softmax_kernel(u16* __restrict__ s)
{
    const int wave = (blockIdx.x << 2) | (threadIdx.x >> 6);
    const int lane = threadIdx.x & 63;
    u16* rowp = s + (size_t)wave * 1024;

    float v[16];
#pragma unroll
    for (int c = 0; c < 4; ++c) {
        const ushort4 raw = *(const ushort4*)(rowp + c * 256 + lane * 4);
        v[c * 4 + 0] = bf2f(raw.x);
        v[c * 4 + 1] = bf2f(raw.y);
        v[c * 4 + 2] = bf2f(raw.z);
        v[c * 4 + 3] = bf2f(raw.w);
    }
    float m = -1e30f;
#pragma unroll
    for (int i = 0; i < 16; ++i) m = fmaxf(m, v[i]);
#pragma unroll
    for (int off = 32; off; off >>= 1) m = fmaxf(m, __shfl_xor(m, off));
    float sum = 0.f;
#pragma unroll
    for (int i = 0; i < 16; ++i) {
        v[i] = __expf(v[i] - m);
        sum += v[i];
    }
#pragma unroll
    for (int off = 32; off; off >>= 1) sum += __shfl_xor(sum, off);
    const float inv = 1.0f / sum;
#pragma unroll
    for (int c = 0; c < 4; ++c) {
        ushort4 o;
        o.x = f2bf(v[c * 4 + 0] * inv);
        o.y = f2bf(v[c * 4 + 1] * inv);
        o.z = f2bf(v[c * 4 + 2] * inv);
        o.w = f2bf(v[c * 4 + 3] * inv);
        *(ushort4*)(rowp + c * 256 + lane * 4) = o;
    }
}

// ---------------------------------------------------------------- launch
extern "C" void kernel_launch(void* const* d_in, const int* in_sizes, int n_in,
                              void* d_out, int out_size, void* d_ws, size_t ws_size,
                              hipStream_t stream)
{
    (void)in_sizes; (void)n_in; (void)out_size; (void)ws_size;
    const float* x   = (const float*)d_in[0];
    const float* nsc = (const float*)d_in[1];
    const float* nbi = (const float*)d_in[2];
    const float* wq  = (const float*)d_in[3];
    const float* bq  = (const float*)d_in[4];
    const float* wk  = (const float*)d_in[5];
    const float* bk  = (const float*)d_in[6];
    const float* wv  = (const float*)d_in[7];
    const float* bv  = (const float*)d_in[8];
    const float* wp  = (const float*)d_in[9];
    const float* bp  = (const float*)d_in[10];
    float* out = (float*)d_out;

    char* ws = (char*)d_ws;
    u16* qb = (u16*)(ws);                        // 32 MB  [32768,512]  (q)
    u16* kb = (u16*)(ws + (32ull << 20));        // 32 MB  [32768,512]  (k)
    u16* vT = (u16*)(ws + (64ull << 20));        // 32 MB  [32,512,1024]
    u16* sb = (u16*)(ws + (96ull << 20));        // 64 MB  [32,1024,1024] (scores)
    u16* hn = (u16*)(ws + (160ull << 20));       // 32 MB  [32768,512]
    u16* ao = hn;                                 // reuse: hn dead after QKV
    u16* wT = (u16*)(ws + (192ull << 20));       // 2 MB   [4*512,512] stacked q,k,v,p
    float2* gnp = (float2*)sb;                   // 64 KB partials (dead before scores)
    float2* gns = (float2*)(ws + (97ull << 20)); // 8 KB stats

    transpose_weights<<<4096, 256, 0, stream>>>(wq, wk, wv, wp, wT);
    gn_partial<<<256, 256, 0, stream>>>(x, gnp);
    gn_stats<<<4, 256, 0, stream>>>(gnp, gns);
    gn_apply<<<16384, 256, 0, stream>>>(x, gns, nsc, nbi, hn);

    const dim3 blk(512);
    // fused QKV: M=32768 (128 strips), N=1536 (6 blocks): 8 XCD * 16 * 6 = 768
    gemm8<4, 6><<<768, blk, 0, stream>>>(hn, wT, qb, vT, bq, bk, bv, nullptr,
                                         512, 512, 0, 0, 0, 1.f);

    const dim3 g2(4, 4, 32);                     // scores: N=1024, M=1024, 32 batches
    gemm8<0, 0><<<g2, blk, 0, stream>>>(qb, kb, sb, nullptr, nullptr, nullptr, nullptr, nullptr,
                                        512, 1024, 1024L * 512, 1024L * 512, 1024L * 1024,
                                        0.04419417382415922f);  // 512^-0.5
    softmax_kernel<<<8192, dim3(256), 0, stream>>>(sb);

    const dim3 g3(2, 4, 32);                     // out: N=512, M=1024, 32 batches
    gemm8<0, 0><<<g3, blk, 0, stream>>>(sb, vT, ao, nullptr, nullptr, nullptr, nullptr, nullptr,
                                        1024, 512, 1024L * 1024, 512L * 1024, 1024L * 512,
                                        1.f);

    // proj: M=32768 (128 strips), N=512 (2 blocks): 8 XCD * 16 * 2 = 256
    gemm8<3, 2><<<256, blk, 0, stream>>>(ao, wT + 3 * 262144, out, nullptr, bp, nullptr, nullptr, x,
                                         512, 512, 0, 0, 0, 1.f);
}

// Round 4
// 368.411 us; speedup vs baseline: 1.1680x; 1.0258x over previous
//
#include <hip/hip_runtime.h>
#include <stdint.h>
#include <stddef.h>

// AttnBlock: x[32,32,32,512] fp32 -> groupnorm(32) -> q/k/v 1x1 conv -> attn(seq=1024) -> proj -> +x
// R9: single-barrier phases. R8's mid-phase barrier forced 8-wave lockstep
// (read-window then MFMA-window, serialized: ~1270cy/phase vs 620cy MFMA).
// Correctness: each wave's phase-p MFMA lgkm-waits its p-reads BEFORE the
// end-of-phase barrier, so one barrier/phase preserves the >=2-barrier
// stage-overwrite discipline and the vmcnt landing gates. 8 barriers/iter
// instead of 16; wave skew now overlaps reads(w1) with MFMA(w2).

typedef short bh8 __attribute__((ext_vector_type(8)));   // 8 bf16 payload (4 VGPRs)
typedef __bf16 bf8 __attribute__((ext_vector_type(8)));  // builtin operand type
typedef float f4 __attribute__((ext_vector_type(4)));
typedef unsigned short u16;

#define NB 32
#define HW 1024
#define NC 512
#define NM (NB * HW)   // 32768 rows total

__device__ __forceinline__ u16 f2bf(float f) {
    union { float f; uint32_t u; } v; v.f = f;
    uint32_t r = v.u + 0x7FFFu + ((v.u >> 16) & 1u);  // RNE
    return (u16)(r >> 16);
}
__device__ __forceinline__ float bf2f(u16 h) {
    union { uint32_t u; float f; } v; v.u = ((uint32_t)h) << 16;
    return v.f;
}

using gas_p = const __attribute__((address_space(1))) void*;
using las_p = __attribute__((address_space(3))) void*;

__device__ __forceinline__ void async16(const void* g, void* l) {
    __builtin_amdgcn_global_load_lds((gas_p)g, (las_p)l, 16, 0, 0);
}

__device__ __forceinline__ f4 mfma16(bh8 a, bh8 b, f4 c) {
    return __builtin_amdgcn_mfma_f32_16x16x32_bf16(
        __builtin_bit_cast(bf8, a), __builtin_bit_cast(bf8, b), c, 0, 0, 0);
}

#define BAR()    __builtin_amdgcn_s_barrier()
#define SBAR()   __builtin_amdgcn_sched_barrier(0)
#define VMCNT(N) asm volatile("s_waitcnt vmcnt(" #N ")")

// ---------------------------------------------------------------- transpose weights
__global__ __launch_bounds__(256) void transpose_weights(
    const float* __restrict__ wq, const float* __restrict__ wk,
    const float* __restrict__ wv, const float* __restrict__ wp,
    u16* __restrict__ wT)
{
    int idx = blockIdx.x * 256 + threadIdx.x;      // 0 .. 4*512*512-1
    int m = idx >> 18;
    int r = idx & 0x3FFFF;                          // r = k*512 + n (coalesced read)
    int k = r >> 9, n = r & 511;
    const float* w = (m == 0) ? wq : (m == 1) ? wk : (m == 2) ? wv : wp;
    wT[((size_t)m << 18) + (size_t)n * 512 + k] = f2bf(w[r]);
}

// ---------------------------------------------------------------- group norm (3 stages)
__global__ __launch_bounds__(256) void gn_partial(
    const float* __restrict__ x, float2* __restrict__ part)
{
    const int b = blockIdx.x >> 3, s = blockIdx.x & 7;
    const int t = threadIdx.x;
    const int c0 = (t & 127) * 4;
    const int pr = t >> 7;
    const float* xb = x + (size_t)b * HW * NC + (size_t)(s * 128) * NC + c0;
    float sum = 0.f, sq = 0.f;
#pragma unroll 8
    for (int i = 0; i < 64; ++i) {
        const float4 v = *(const float4*)(xb + (size_t)(pr + i * 2) * NC);
        sum += v.x + v.y + v.z + v.w;
        sq  += v.x * v.x + v.y * v.y + v.z * v.z + v.w * v.w;
    }
    __shared__ float2 red[256];
    red[t] = make_float2(sum, sq);
    __syncthreads();
    if (t < 32) {
        float S = 0.f, Q = 0.f;
#pragma unroll
        for (int p = 0; p < 2; ++p)
#pragma unroll
            for (int j = 0; j < 4; ++j) {
                const float2 v = red[t * 4 + j + p * 128];
                S += v.x; Q += v.y;
            }
        part[(size_t)blockIdx.x * 32 + t] = make_float2(S, Q);
    }
}

__global__ __launch_bounds__(256) void gn_stats(
    const float2* __restrict__ part, float2* __restrict__ stats)
{
    const int p = blockIdx.x * 256 + threadIdx.x;   // 0..1023
    const int b = p >> 5, g = p & 31;
    float S = 0.f, Q = 0.f;
#pragma unroll
    for (int s = 0; s < 8; ++s) {
        const float2 v = part[((size_t)(b * 8 + s)) * 32 + g];
        S += v.x; Q += v.y;
    }
    const float mean = S * (1.f / 16384.f);
    const float var = Q * (1.f / 16384.f) - mean * mean;
    stats[p] = make_float2(mean, rsqrtf(var + 1e-6f));
}

__global__ __launch_bounds__(256) void gn_apply(
    const float* __restrict__ x, const float2* __restrict__ stats,
    const float* __restrict__ scale, const float* __restrict__ bias,
    u16* __restrict__ hn)
{
    const size_t idx = (size_t)blockIdx.x * 256 + threadIdx.x;  // float4 index
    const size_t e = idx * 4;
    const int c0 = (int)(e & 511);
    const int bg = (int)(e >> 19) * 32 + (c0 >> 4);
    const float2 st = stats[bg];
    const float4 v = *(const float4*)(x + e);
    const float4 sc = *(const float4*)(scale + c0);
    const float4 bi = *(const float4*)(bias + c0);
    ushort4 o;
    o.x = f2bf((v.x - st.x) * st.y * sc.x + bi.x);
    o.y = f2bf((v.y - st.x) * st.y * sc.y + bi.y);
    o.z = f2bf((v.z - st.x) * st.y * sc.z + bi.z);
    o.w = f2bf((v.w - st.x) * st.y * sc.w + bi.w);
    *(ushort4*)(hn + e) = o;
}

// ---------------------------------------------------------------- 8-phase 256x256 GEMM
// C[M,N] = A[M,K] * Bt[N,K]^T, bf16 in, fp32 accum. BM=BN=256, BK=64.
// 512 threads = 8 waves (2M x 4N); per wave 128x64 output = 8x4 16x16 frags.
// LDS: 2 K-tile buffers x (A[256][64] + B[256][64]) bf16 = 128 KiB.
// Swizzle: 16B-chunk c at row stored at phys chunk c ^ (row&7); staged via
// pre-swizzled GLOBAL source (global_load_lds dest is linear), read with XOR.
//
// Phase table (gray-coded quadrants; LA/LB = load A/B frags from LDS; ONE
// barrier at phase end):
//  P  buf QM QN LA LB | stages (region <- K-tile)
//  0   0   0  0  1  1 | buf1.Aq1 <- kt+1
//  1   0   0  1  0  1 | buf1.Bq0 <- kt+1
//  2   0   1  1  1  0 | buf0.Aq0 <- kt+2  [it<NI-1]
//  3   0   1  0  0  1 | buf0.Bq1 <- kt+2  [g]  VMCNT(4|0)
//  4   1   0  0  1  1 | buf0.Aq1 <- kt+2  [g]
//  5   1   0  1  0  1 | buf0.Bq0 <- kt+2  [g]
//  6   1   1  1  1  0 | buf1.Aq0 <- kt+3  [g]
//  7   1   1  0  0  1 | buf1.Bq1 <- kt+3  [g]  VMCNT(4)
// Safety: a wave's phase-p MFMA lgkm-waits its p ds_reads before reaching the
// end barrier, so passing BAR(end-p) implies ALL waves' p-reads completed.
// Every staged region's last read is >=2 end-barriers before its stage issue.
// vmcnt ledger (2 loads/wave/stage): p3's VMCNT(4) leaves p2,p3 in flight ->
// prev{p6,p7}+p0,p1 landed -> buf1(kt+1) ready before p4 reads it (after
// BAR(end-p3) joins all waves' gates). p7's VMCNT(4) leaves p6,p7 -> p2..p5
// landed -> buf0(kt+2) ready for next p0. Last iter: p3 VMCNT(0).

template <int MAT, int Q>
__device__ __forceinline__ void stage_region(u16* ldsmat, const u16* g, int ldG,
                                             int w, int lane) {
#pragma unroll
    for (int j = 0; j < 2; ++j) {
        const int rowbase = (MAT == 0)
            ? (j * 128 + Q * 64 + w * 8)
            : ((j * 2 + (w >> 2)) * 64 + Q * 32 + (w & 3) * 8);
        const int row = rowbase + (lane >> 3);
        const int c16 = (lane & 7) ^ (lane >> 3);       // inverse swizzle on source
        async16(g + (size_t)row * ldG + (c16 << 3), ldsmat + rowbase * 64);
    }
}

#define PHASE(P, D, QM, QN, LA, LB, SD, SMAT, SQ, SKT, GRD)                        \
    {                                                                              \
        if (LA) {                                                                  \
            _Pragma("unroll") for (int mt = 0; mt < 4; ++mt) {                     \
                const int arow = wm * 128 + (QM) * 64 + mt * 16 + r;               \
                _Pragma("unroll") for (int kk = 0; kk < 2; ++kk)                   \
                    paf[mt][kk] = *(const bh8*)&lds[D][0][arow * 64 +              \
                        (((kk * 4 + q4) ^ (r & 7)) << 3)];                         \
            }                                                                      \
        }                                                                          \
        if (LB) {                                                                  \
            _Pragma("unroll") for (int nt = 0; nt < 2; ++nt) {                     \
                const int brow = wn * 64 + (QN) * 32 + nt * 16 + r;                \
                _Pragma("unroll") for (int kk = 0; kk < 2; ++kk)                   \
                    pbf[nt][kk] = *(const bh8*)&lds[D][1][brow * 64 +              \
                        (((kk * 4 + q4) ^ (r & 7)) << 3)];                         \
            }                                                                      \
        }                                                                          \
        if (!(GRD) || it < NI - 1) {                                               \
            const size_t ko = (size_t)(2 * it + (SKT)) << 6;                       \
            if ((SMAT) == 0) stage_region<0, SQ>(&lds[SD][0][0], A_ + ko, K, wid, lane); \
            else             stage_region<1, SQ>(&lds[SD][1][0], B_ + ko, K, wid, lane); \
        }                                                                          \
        __builtin_amdgcn_s_setprio(1);                                             \
        _Pragma("unroll") for (int mt = 0; mt < 4; ++mt)                           \
            _Pragma("unroll") for (int nt = 0; nt < 2; ++nt)                       \
                _Pragma("unroll") for (int kk = 0; kk < 2; ++kk)                   \
                    acc[(QM) * 4 + mt][(QN) * 2 + nt] =                            \
                        mfma16(paf[mt][kk], pbf[nt][kk],                           \
                               acc[(QM) * 4 + mt][(QN) * 2 + nt]);                 \
        __builtin_amdgcn_s_setprio(0);                                             \
        if ((P) == 3) { if (it < NI - 1) { VMCNT(4); } else { VMCNT(0); } }        \
        if ((P) == 7) { VMCNT(4); }                                                \
        BAR();                                                                     \
        SBAR();                                                                    \
    }

// MODE 0: bf16 C0 = alpha*acc (batched via blockIdx.z)
// MODE 3: fp32 C0 = acc + b0[col] + resid[row*ldc+col]
// MODE 4: fused QKV: col<1024 -> q/k (seg-strided); col>=1024 -> vT transposed
// SWZ > 0: 1D grid of 8*mper*SWZ blocks; xcd = bid&7; same mapping as before.
template <int MODE, int SWZ>
__global__ __launch_bounds__(512, 2) void gemm8(
    const u16* __restrict__ A, const u16* __restrict__ Bt,
    void* __restrict__ C0, void* __restrict__ C1,
    const float* __restrict__ b0, const float* __restrict__ b1,
    const float* __restrict__ b2, const float* __restrict__ resid,
    int K, int ldc, long strA, long strB, long strC, float alpha)
{
    __shared__ __align__(16) u16 lds[2][2][256 * 64];   // 128 KiB
    const int tid = threadIdx.x;
    const int wid = tid >> 6, lane = tid & 63;
    const int wm = wid >> 2, wn = wid & 3;              // 2 x 4 wave grid
    const int r = lane & 15, q4 = lane >> 4;
    const int z = blockIdx.z;

    int m0, n0;
    if (SWZ > 0) {
        const int g = blockIdx.x;
        const int xcd = g & 7, s = g >> 3;
        const int mper = (int)(gridDim.x >> 3) / SWZ;
        m0 = (xcd * mper + s / SWZ) * 256;
        n0 = (s % SWZ) * 256;
    } else {
        m0 = blockIdx.y * 256;
        n0 = blockIdx.x * 256;
    }

    const u16* A_ = A + (size_t)z * strA + (size_t)m0 * K;
    const u16* B_ = Bt + (size_t)z * strB + (size_t)n0 * K;

    f4 acc[8][4];
#pragma unroll
    for (int ii = 0; ii < 8; ++ii)
#pragma unroll
        for (int jj = 0; jj < 4; ++jj) {
            f4 zr = {0.f, 0.f, 0.f, 0.f};
            acc[ii][jj] = zr;
        }
    bh8 paf[4][2], pbf[2][2];                            // persistent fragments

    const int NI = K >> 7;   // 2 K-tiles (of 64) per iteration; K in {512,1024}

    // prologue: issue order == steady-state p2..p7 (vmcnt counting relies on it)
    stage_region<0, 0>(&lds[0][0][0], A_,      K, wid, lane);  // buf0.Aq0 kt0
    stage_region<1, 1>(&lds[0][1][0], B_,      K, wid, lane);  // buf0.Bq1 kt0
    stage_region<0, 1>(&lds[0][0][0], A_,      K, wid, lane);  // buf0.Aq1 kt0
    stage_region<1, 0>(&lds[0][1][0], B_,      K, wid, lane);  // buf0.Bq0 kt0
    stage_region<0, 0>(&lds[1][0][0], A_ + 64, K, wid, lane);  // buf1.Aq0 kt1
    stage_region<1, 1>(&lds[1][1][0], B_ + 64, K, wid, lane);  // buf1.Bq1 kt1
    VMCNT(4);   // buf0 fully landed; buf1.Aq0/Bq1 may remain in flight
    BAR();
    SBAR();

    for (int it = 0; it < NI; ++it) {
        PHASE(0, 0, 0, 0, 1, 1, 1, 0, 1, 1, 0)
        PHASE(1, 0, 0, 1, 0, 1, 1, 1, 0, 1, 0)
        PHASE(2, 0, 1, 1, 1, 0, 0, 0, 0, 2, 1)
        PHASE(3, 0, 1, 0, 0, 1, 0, 1, 1, 2, 1)
        PHASE(4, 1, 0, 0, 1, 1, 0, 0, 1, 2, 1)
        PHASE(5, 1, 0, 1, 0, 1, 0, 1, 0, 2, 1)
        PHASE(6, 1, 1, 1, 1, 0, 1, 0, 0, 3, 1)
        PHASE(7, 1, 1, 0, 0, 1, 1, 1, 1, 3, 1)
    }

    // epilogue: C/D layout col = lane&15, row = (lane>>4)*4 + i
#pragma unroll
    for (int am = 0; am < 8; ++am) {
#pragma unroll
        for (int an = 0; an < 4; ++an) {
            const int col = n0 + wn * 64 + an * 16 + r;
            const int row0 = m0 + wm * 128 + am * 16 + q4 * 4;
            if (MODE == 0) {
#pragma unroll
                for (int i2 = 0; i2 < 4; ++i2)
                    ((u16*)C0)[(size_t)z * strC + (size_t)(row0 + i2) * ldc + col] =
                        f2bf(acc[am][an][i2] * alpha);
            } else if (MODE == 3) {
                const float bv = b0[col];
#pragma unroll
                for (int i2 = 0; i2 < 4; ++i2) {
                    const size_t idx = (size_t)(row0 + i2) * ldc + col;
                    ((float*)C0)[idx] = acc[am][an][i2] + bv + resid[idx];
                }
            } else {  // MODE 4: fused QKV
                const int seg = col >> 9, cl = col & 511;
                const float bv = (seg == 0 ? b0 : seg == 1 ? b1 : b2)[cl];
                if (seg < 2) {
                    u16* base = (u16*)C0 + (size_t)seg * (size_t)NM * 512;
#pragma unroll
                    for (int i2 = 0; i2 < 4; ++i2)
                        base[(size_t)(row0 + i2) * 512 + cl] = f2bf(acc[am][an][i2] + bv);
                } else {
                    const int bb = row0 >> 10, ml = row0 & 1023;
                    ushort4 o;
                    o.x = f2bf(acc[am][an][0] + bv);
                    o.y = f2bf(acc[am][an][1] + bv);
                    o.z = f2bf(acc[am][an][2] + bv);
                    o.w = f2bf(acc[am][an][3] + bv);
                    *(ushort4*)((u16*)C1 + ((size_t)(bb * 512 + cl)) * 1024 + ml) = o;
                }
            }
        }
    }
}

// ---------------------------------------------------------------- softmax (in place)
__global__ __launch_bounds__(256) void softmax_kernel(u16* __restrict__ s)
{
    const int wave = (blockIdx.x << 2) | (threadIdx.x >> 6);
    const int lane = threadIdx.x & 63;
    u16* rowp = s + (size_t)wave * 1024;

    float v[16];
#pragma unroll
    for (int c = 0; c < 4; ++c) {
        const ushort4 raw = *(const ushort4*)(rowp + c * 256 + lane * 4);
        v[c * 4 + 0] = bf2f(raw.x);
        v[c * 4 + 1] = bf2f(raw.y);
        v[c * 4 + 2] = bf2f(raw.z);
        v[c * 4 + 3] = bf2f(raw.w);
    }
    float m = -1e30f;
#pragma unroll
    for (int i = 0; i < 16; ++i) m = fmaxf(m, v[i]);
#pragma unroll
    for (int off = 32; off; off >>= 1) m = fmaxf(m, __shfl_xor(m, off));
    float sum = 0.f;
#pragma unroll
    for (int i = 0; i < 16; ++i) {
        v[i] = __expf(v[i] - m);
        sum += v[i];
    }
#pragma unroll
    for (int off = 32; off; off >>= 1) sum += __shfl_xor(sum, off);
    const float inv = 1.0f / sum;
#pragma unroll
    for (int c = 0; c < 4; ++c) {
        ushort4 o;
        o.x = f2bf(v[c * 4 + 0] * inv);
        o.y = f2bf(v[c * 4 + 1] * inv);
        o.z = f2bf(v[c * 4 + 2] * inv);
        o.w = f2bf(v[c * 4 + 3] * inv);
        *(ushort4*)(rowp + c * 256 + lane * 4) = o;
    }
}

// ---------------------------------------------------------------- launch
extern "C" void kernel_launch(void* const* d_in, const int* in_sizes, int n_in,
                              void* d_out, int out_size, void* d_ws, size_t ws_size,
                              hipStream_t stream)
{
    (void)in_sizes; (void)n_in; (void)out_size; (void)ws_size;
    const float* x   = (const float*)d_in[0];
    const float* nsc = (const float*)d_in[1];
    const float* nbi = (const float*)d_in[2];
    const float* wq  = (const float*)d_in[3];
    const float* bq  = (const float*)d_in[4];
    const float* wk  = (const float*)d_in[5];
    const float* bk  = (const float*)d_in[6];
    const float* wv  = (const float*)d_in[7];
    const float* bv  = (const float*)d_in[8];
    const float* wp  = (const float*)d_in[9];
    const float* bp  = (const float*)d_in[10];
    float* out = (float*)d_out;

    char* ws = (char*)d_ws;
    u16* qb = (u16*)(ws);                        // 32 MB  [32768,512]  (q)
    u16* kb = (u16*)(ws + (32ull << 20));        // 32 MB  [32768,512]  (k)
    u16* vT = (u16*)(ws + (64ull << 20));        // 32 MB  [32,512,1024]
    u16* sb = (u16*)(ws + (96ull << 20));        // 64 MB  [32,1024,1024] (scores)
    u16* hn = (u16*)(ws + (160ull << 20));       // 32 MB  [32768,512]
    u16* ao = hn;                                 // reuse: hn dead after QKV
    u16* wT = (u16*)(ws + (192ull << 20));       // 2 MB   [4*512,512] stacked q,k,v,p
    float2* gnp = (float2*)sb;                   // 64 KB partials (dead before scores)
    float2* gns = (float2*)(ws + (97ull << 20)); // 8 KB stats

    transpose_weights<<<4096, 256, 0, stream>>>(wq, wk, wv, wp, wT);
    gn_partial<<<256, 256, 0, stream>>>(x, gnp);
    gn_stats<<<4, 256, 0, stream>>>(gnp, gns);
    gn_apply<<<16384, 256, 0, stream>>>(x, gns, nsc, nbi, hn);

    const dim3 blk(512);
    // fused QKV: M=32768 (128 strips), N=1536 (6 blocks): 8 XCD * 16 * 6 = 768
    gemm8<4, 6><<<768, blk, 0, stream>>>(hn, wT, qb, vT, bq, bk, bv, nullptr,
                                         512, 512, 0, 0, 0, 1.f);

    const dim3 g2(4, 4, 32);                     // scores: N=1024, M=1024, 32 batches
    gemm8<0, 0><<<g2, blk, 0, stream>>>(qb, kb, sb, nullptr, nullptr, nullptr, nullptr, nullptr,
                                        512, 1024, 1024L * 512, 1024L * 512, 1024L * 1024,
                                        0.04419417382415922f);  // 512^-0.5
    softmax_kernel<<<8192, dim3(256), 0, stream>>>(sb);

    const dim3 g3(2, 4, 32);                     // out: N=512, M=1024, 32 batches
    gemm8<0, 0><<<g3, blk, 0, stream>>>(sb, vT, ao, nullptr, nullptr, nullptr, nullptr, nullptr,
                                        1024, 512, 1024L * 1024, 512L * 1024, 1024L * 512,
                                        1.f);

    // proj: M=32768 (128 strips), N=512 (2 blocks): 8 XCD * 16 * 2 = 256
    gemm8<3, 2><<<256, blk, 0, stream>>>(ao, wT + 3 * 262144, out, nullptr, bp, nullptr, nullptr, x,
                                         512, 512, 0, 0, 0, 1.f);
}

// Round 5
// 368.371 us; speedup vs baseline: 1.1681x; 1.0001x over previous
//
#include <hip/hip_runtime.h>
#include <stdint.h>
#include <stddef.h>

// AttnBlock: x[32,32,32,512] fp32 -> groupnorm(32) -> q/k/v 1x1 conv -> attn(seq=1024) -> proj -> +x
// R10: per-GEMM barrier style (template MB), recombining measured winners:
//  - QKV (MB=1): R8's two-barrier phase -> measured 80.6us (R9's 1-barrier: 100.4)
//  - scores/attnV/proj (MB=0): R9's single-barrier phase -> combined -29us vs R8
// Everything else identical to R9.

typedef short bh8 __attribute__((ext_vector_type(8)));   // 8 bf16 payload (4 VGPRs)
typedef __bf16 bf8 __attribute__((ext_vector_type(8)));  // builtin operand type
typedef float f4 __attribute__((ext_vector_type(4)));
typedef unsigned short u16;

#define NB 32
#define HW 1024
#define NC 512
#define NM (NB * HW)   // 32768 rows total

__device__ __forceinline__ u16 f2bf(float f) {
    union { float f; uint32_t u; } v; v.f = f;
    uint32_t r = v.u + 0x7FFFu + ((v.u >> 16) & 1u);  // RNE
    return (u16)(r >> 16);
}
__device__ __forceinline__ float bf2f(u16 h) {
    union { uint32_t u; float f; } v; v.u = ((uint32_t)h) << 16;
    return v.f;
}

using gas_p = const __attribute__((address_space(1))) void*;
using las_p = __attribute__((address_space(3))) void*;

__device__ __forceinline__ void async16(const void* g, void* l) {
    __builtin_amdgcn_global_load_lds((gas_p)g, (las_p)l, 16, 0, 0);
}

__device__ __forceinline__ f4 mfma16(bh8 a, bh8 b, f4 c) {
    return __builtin_amdgcn_mfma_f32_16x16x32_bf16(
        __builtin_bit_cast(bf8, a), __builtin_bit_cast(bf8, b), c, 0, 0, 0);
}

#define BAR()    __builtin_amdgcn_s_barrier()
#define SBAR()   __builtin_amdgcn_sched_barrier(0)
#define VMCNT(N) asm volatile("s_waitcnt vmcnt(" #N ")")

// ---------------------------------------------------------------- transpose weights
__global__ __launch_bounds__(256) void transpose_weights(
    const float* __restrict__ wq, const float* __restrict__ wk,
    const float* __restrict__ wv, const float* __restrict__ wp,
    u16* __restrict__ wT)
{
    int idx = blockIdx.x * 256 + threadIdx.x;      // 0 .. 4*512*512-1
    int m = idx >> 18;
    int r = idx & 0x3FFFF;                          // r = k*512 + n (coalesced read)
    int k = r >> 9, n = r & 511;
    const float* w = (m == 0) ? wq : (m == 1) ? wk : (m == 2) ? wv : wp;
    wT[((size_t)m << 18) + (size_t)n * 512 + k] = f2bf(w[r]);
}

// ---------------------------------------------------------------- group norm (3 stages)
__global__ __launch_bounds__(256) void gn_partial(
    const float* __restrict__ x, float2* __restrict__ part)
{
    const int b = blockIdx.x >> 3, s = blockIdx.x & 7;
    const int t = threadIdx.x;
    const int c0 = (t & 127) * 4;
    const int pr = t >> 7;
    const float* xb = x + (size_t)b * HW * NC + (size_t)(s * 128) * NC + c0;
    float sum = 0.f, sq = 0.f;
#pragma unroll 8
    for (int i = 0; i < 64; ++i) {
        const float4 v = *(const float4*)(xb + (size_t)(pr + i * 2) * NC);
        sum += v.x + v.y + v.z + v.w;
        sq  += v.x * v.x + v.y * v.y + v.z * v.z + v.w * v.w;
    }
    __shared__ float2 red[256];
    red[t] = make_float2(sum, sq);
    __syncthreads();
    if (t < 32) {
        float S = 0.f, Q = 0.f;
#pragma unroll
        for (int p = 0; p < 2; ++p)
#pragma unroll
            for (int j = 0; j < 4; ++j) {
                const float2 v = red[t * 4 + j + p * 128];
                S += v.x; Q += v.y;
            }
        part[(size_t)blockIdx.x * 32 + t] = make_float2(S, Q);
    }
}

__global__ __launch_bounds__(256) void gn_stats(
    const float2* __restrict__ part, float2* __restrict__ stats)
{
    const int p = blockIdx.x * 256 + threadIdx.x;   // 0..1023
    const int b = p >> 5, g = p & 31;
    float S = 0.f, Q = 0.f;
#pragma unroll
    for (int s = 0; s < 8; ++s) {
        const float2 v = part[((size_t)(b * 8 + s)) * 32 + g];
        S += v.x; Q += v.y;
    }
    const float mean = S * (1.f / 16384.f);
    const float var = Q * (1.f / 16384.f) - mean * mean;
    stats[p] = make_float2(mean, rsqrtf(var + 1e-6f));
}

__global__ __launch_bounds__(256) void gn_apply(
    const float* __restrict__ x, const float2* __restrict__ stats,
    const float* __restrict__ scale, const float* __restrict__ bias,
    u16* __restrict__ hn)
{
    const size_t idx = (size_t)blockIdx.x * 256 + threadIdx.x;  // float4 index
    const size_t e = idx * 4;
    const int c0 = (int)(e & 511);
    const int bg = (int)(e >> 19) * 32 + (c0 >> 4);
    const float2 st = stats[bg];
    const float4 v = *(const float4*)(x + e);
    const float4 sc = *(const float4*)(scale + c0);
    const float4 bi = *(const float4*)(bias + c0);
    ushort4 o;
    o.x = f2bf((v.x - st.x) * st.y * sc.x + bi.x);
    o.y = f2bf((v.y - st.x) * st.y * sc.y + bi.y);
    o.z = f2bf((v.z - st.x) * st.y * sc.z + bi.z);
    o.w = f2bf((v.w - st.x) * st.y * sc.w + bi.w);
    *(ushort4*)(hn + e) = o;
}

// ---------------------------------------------------------------- 8-phase 256x256 GEMM
// C[M,N] = A[M,K] * Bt[N,K]^T, bf16 in, fp32 accum. BM=BN=256, BK=64.
// 512 threads = 8 waves (2M x 4N); per wave 128x64 output = 8x4 16x16 frags.
// LDS: 2 K-tile buffers x (A[256][64] + B[256][64]) bf16 = 128 KiB.
// Swizzle: 16B-chunk c at row stored at phys chunk c ^ (row&7); staged via
// pre-swizzled GLOBAL source (global_load_lds dest is linear), read with XOR.
//
// Phase table (gray-coded quadrants; LA/LB = load A/B frags from LDS):
//  P  buf QM QN LA LB | stages (region <- K-tile)
//  0   0   0  0  1  1 | buf1.Aq1 <- kt+1
//  1   0   0  1  0  1 | buf1.Bq0 <- kt+1
//  2   0   1  1  1  0 | buf0.Aq0 <- kt+2  [it<NI-1]
//  3   0   1  0  0  1 | buf0.Bq1 <- kt+2  [g]  VMCNT(4|0)
//  4   1   0  0  1  1 | buf0.Aq1 <- kt+2  [g]
//  5   1   0  1  0  1 | buf0.Bq0 <- kt+2  [g]
//  6   1   1  1  1  0 | buf1.Aq0 <- kt+3  [g]
//  7   1   1  0  0  1 | buf1.Bq1 <- kt+3  [g]  VMCNT(4)
// MB=1 (R8 style): BAR after reads+stage, MFMA, vmcnt+SBAR, BAR  (best for QKV)
// MB=0 (R9 style): reads+stage, MFMA, vmcnt, BAR, SBAR           (best for others)
// Safety (both): a wave's phase-p MFMA lgkm-waits its p ds_reads before the
// end barrier; every staged region's last read is >=2 end-barriers before its
// stage issue. vmcnt ledger (2 loads/wave/stage): p3's VMCNT(4) -> buf1(kt+1)
// landed before p4; p7's VMCNT(4) -> buf0(kt+2) landed before next p0.

template <int MAT, int Q>
__device__ __forceinline__ void stage_region(u16* ldsmat, const u16* g, int ldG,
                                             int w, int lane) {
#pragma unroll
    for (int j = 0; j < 2; ++j) {
        const int rowbase = (MAT == 0)
            ? (j * 128 + Q * 64 + w * 8)
            : ((j * 2 + (w >> 2)) * 64 + Q * 32 + (w & 3) * 8);
        const int row = rowbase + (lane >> 3);
        const int c16 = (lane & 7) ^ (lane >> 3);       // inverse swizzle on source
        async16(g + (size_t)row * ldG + (c16 << 3), ldsmat + rowbase * 64);
    }
}

#define PHASE(P, D, QM, QN, LA, LB, SD, SMAT, SQ, SKT, GRD)                        \
    {                                                                              \
        if (LA) {                                                                  \
            _Pragma("unroll") for (int mt = 0; mt < 4; ++mt) {                     \
                const int arow = wm * 128 + (QM) * 64 + mt * 16 + r;               \
                _Pragma("unroll") for (int kk = 0; kk < 2; ++kk)                   \
                    paf[mt][kk] = *(const bh8*)&lds[D][0][arow * 64 +              \
                        (((kk * 4 + q4) ^ (r & 7)) << 3)];                         \
            }                                                                      \
        }                                                                          \
        if (LB) {                                                                  \
            _Pragma("unroll") for (int nt = 0; nt < 2; ++nt) {                     \
                const int brow = wn * 64 + (QN) * 32 + nt * 16 + r;                \
                _Pragma("unroll") for (int kk = 0; kk < 2; ++kk)                   \
                    pbf[nt][kk] = *(const bh8*)&lds[D][1][brow * 64 +              \
                        (((kk * 4 + q4) ^ (r & 7)) << 3)];                         \
            }                                                                      \
        }                                                                          \
        if (!(GRD) || it < NI - 1) {                                               \
            const size_t ko = (size_t)(2 * it + (SKT)) << 6;                       \
            if ((SMAT) == 0) stage_region<0, SQ>(&lds[SD][0][0], A_ + ko, K, wid, lane); \
            else             stage_region<1, SQ>(&lds[SD][1][0], B_ + ko, K, wid, lane); \
        }                                                                          \
        if (MB) { BAR(); }                                                         \
        __builtin_amdgcn_s_setprio(1);                                             \
        _Pragma("unroll") for (int mt = 0; mt < 4; ++mt)                           \
            _Pragma("unroll") for (int nt = 0; nt < 2; ++nt)                       \
                _Pragma("unroll") for (int kk = 0; kk < 2; ++kk)                   \
                    acc[(QM) * 4 + mt][(QN) * 2 + nt] =                            \
                        mfma16(paf[mt][kk], pbf[nt][kk],                           \
                               acc[(QM) * 4 + mt][(QN) * 2 + nt]);                 \
        __builtin_amdgcn_s_setprio(0);                                             \
        if ((P) == 3) { if (it < NI - 1) { VMCNT(4); } else { VMCNT(0); }          \
                        if (MB) { SBAR(); } }                                      \
        if ((P) == 7) { VMCNT(4); if (MB) { SBAR(); } }                            \
        BAR();                                                                     \
        if (!(MB)) { SBAR(); }                                                     \
    }

// MODE 0: bf16 C0 = alpha*acc (batched via blockIdx.z)
// MODE 3: fp32 C0 = acc + b0[col] + resid[row*ldc+col]
// MODE 4: fused QKV: col<1024 -> q/k (seg-strided); col>=1024 -> vT transposed
// SWZ > 0: 1D grid of 8*mper*SWZ blocks; xcd = bid&7; same mapping as before.
template <int MODE, int SWZ, int MB>
__global__ __launch_bounds__(512, 2) void gemm8(
    const u16* __restrict__ A, const u16* __restrict__ Bt,
    void* __restrict__ C0, void* __restrict__ C1,
    const float* __restrict__ b0, const float* __restrict__ b1,
    const float* __restrict__ b2, const float* __restrict__ resid,
    int K, int ldc, long strA, long strB, long strC, float alpha)
{
    __shared__ __align__(16) u16 lds[2][2][256 * 64];   // 128 KiB
    const int tid = threadIdx.x;
    const int wid = tid >> 6, lane = tid & 63;
    const int wm = wid >> 2, wn = wid & 3;              // 2 x 4 wave grid
    const int r = lane & 15, q4 = lane >> 4;
    const int z = blockIdx.z;

    int m0, n0;
    if (SWZ > 0) {
        const int g = blockIdx.x;
        const int xcd = g & 7, s = g >> 3;
        const int mper = (int)(gridDim.x >> 3) / SWZ;
        m0 = (xcd * mper + s / SWZ) * 256;
        n0 = (s % SWZ) * 256;
    } else {
        m0 = blockIdx.y * 256;
        n0 = blockIdx.x * 256;
    }

    const u16* A_ = A + (size_t)z * strA + (size_t)m0 * K;
    const u16* B_ = Bt + (size_t)z * strB + (size_t)n0 * K;

    f4 acc[8][4];
#pragma unroll
    for (int ii = 0; ii < 8; ++ii)
#pragma unroll
        for (int jj = 0; jj < 4; ++jj) {
            f4 zr = {0.f, 0.f, 0.f, 0.f};
            acc[ii][jj] = zr;
        }
    bh8 paf[4][2], pbf[2][2];                            // persistent fragments

    const int NI = K >> 7;   // 2 K-tiles (of 64) per iteration; K in {512,1024}

    // prologue: issue order == steady-state p2..p7 (vmcnt counting relies on it)
    stage_region<0, 0>(&lds[0][0][0], A_,      K, wid, lane);  // buf0.Aq0 kt0
    stage_region<1, 1>(&lds[0][1][0], B_,      K, wid, lane);  // buf0.Bq1 kt0
    stage_region<0, 1>(&lds[0][0][0], A_,      K, wid, lane);  // buf0.Aq1 kt0
    stage_region<1, 0>(&lds[0][1][0], B_,      K, wid, lane);  // buf0.Bq0 kt0
    stage_region<0, 0>(&lds[1][0][0], A_ + 64, K, wid, lane);  // buf1.Aq0 kt1
    stage_region<1, 1>(&lds[1][1][0], B_ + 64, K, wid, lane);  // buf1.Bq1 kt1
    VMCNT(4);   // buf0 fully landed; buf1.Aq0/Bq1 may remain in flight
    if (MB) { SBAR(); }
    BAR();
    if (!MB) { SBAR(); }

    for (int it = 0; it < NI; ++it) {
        PHASE(0, 0, 0, 0, 1, 1, 1, 0, 1, 1, 0)
        PHASE(1, 0, 0, 1, 0, 1, 1, 1, 0, 1, 0)
        PHASE(2, 0, 1, 1, 1, 0, 0, 0, 0, 2, 1)
        PHASE(3, 0, 1, 0, 0, 1, 0, 1, 1, 2, 1)
        PHASE(4, 1, 0, 0, 1, 1, 0, 0, 1, 2, 1)
        PHASE(5, 1, 0, 1, 0, 1, 0, 1, 0, 2, 1)
        PHASE(6, 1, 1, 1, 1, 0, 1, 0, 0, 3, 1)
        PHASE(7, 1, 1, 0, 0, 1, 1, 1, 1, 3, 1)
    }

    // epilogue: C/D layout col = lane&15, row = (lane>>4)*4 + i
#pragma unroll
    for (int am = 0; am < 8; ++am) {
#pragma unroll
        for (int an = 0; an < 4; ++an) {
            const int col = n0 + wn * 64 + an * 16 + r;
            const int row0 = m0 + wm * 128 + am * 16 + q4 * 4;
            if (MODE == 0) {
#pragma unroll
                for (int i2 = 0; i2 < 4; ++i2)
                    ((u16*)C0)[(size_t)z * strC + (size_t)(row0 + i2) * ldc + col] =
                        f2bf(acc[am][an][i2] * alpha);
            } else if (MODE == 3) {
                const float bv = b0[col];
#pragma unroll
                for (int i2 = 0; i2 < 4; ++i2) {
                    const size_t idx = (size_t)(row0 + i2) * ldc + col;
                    ((float*)C0)[idx] = acc[am][an][i2] + bv + resid[idx];
                }
            } else {  // MODE 4: fused QKV
                const int seg = col >> 9, cl = col & 511;
                const float bv = (seg == 0 ? b0 : seg == 1 ? b1 : b2)[cl];
                if (seg < 2) {
                    u16* base = (u16*)C0 + (size_t)seg * (size_t)NM * 512;
#pragma unroll
                    for (int i2 = 0; i2 < 4; ++i2)
                        base[(size_t)(row0 + i2) * 512 + cl] = f2bf(acc[am][an][i2] + bv);
                } else {
                    const int bb = row0 >> 10, ml = row0 & 1023;
                    ushort4 o;
                    o.x = f2bf(acc[am][an][0] + bv);
                    o.y = f2bf(acc[am][an][1] + bv);
                    o.z = f2bf(acc[am][an][2] + bv);
                    o.w = f2bf(acc[am][an][3] + bv);
                    *(ushort4*)((u16*)C1 + ((size_t)(bb * 512 + cl)) * 1024 + ml) = o;
                }
            }
        }
    }
}

// ---------------------------------------------------------------- softmax (in place)
__global__ __launch_bounds__(256) void softmax_kernel(u16* __restrict__ s)
{
    const int wave = (blockIdx.x << 2) | (threadIdx.x >> 6);
    const int lane = threadIdx.x & 63;
    u16* rowp = s + (size_t)wave * 1024;

    float v[16];
#pragma unroll
    for (int c = 0; c < 4; ++c) {
        const ushort4 raw = *(const ushort4*)(rowp + c * 256 + lane * 4);
        v[c * 4 + 0] = bf2f(raw.x);
        v[c * 4 + 1] = bf2f(raw.y);
        v[c * 4 + 2] = bf2f(raw.z);
        v[c * 4 + 3] = bf2f(raw.w);
    }
    float m = -1e30f;
#pragma unroll
    for (int i = 0; i < 16; ++i) m = fmaxf(m, v[i]);
#pragma unroll
    for (int off = 32; off; off >>= 1) m = fmaxf(m, __shfl_xor(m, off));
    float sum = 0.f;
#pragma unroll
    for (int i = 0; i < 16; ++i) {
        v[i] = __expf(v[i] - m);
        sum += v[i];
    }
#pragma unroll
    for (int off = 32; off; off >>= 1) sum += __shfl_xor(sum, off);
    const float inv = 1.0f / sum;
#pragma unroll
    for (int c = 0; c < 4; ++c) {
        ushort4 o;
        o.x = f2bf(v[c * 4 + 0] * inv);
        o.y = f2bf(v[c * 4 + 1] * inv);
        o.z = f2bf(v[c * 4 + 2] * inv);
        o.w = f2bf(v[c * 4 + 3] * inv);
        *(ushort4*)(rowp + c * 256 + lane * 4) = o;
    }
}

// ---------------------------------------------------------------- launch
extern "C" void kernel_launch(void* const* d_in, const int* in_sizes, int n_in,
                              void* d_out, int out_size, void* d_ws, size_t ws_size,
                              hipStream_t stream)
{
    (void)in_sizes; (void)n_in; (void)out_size; (void)ws_size;
    const float* x   = (const float*)d_in[0];
    const float* nsc = (const float*)d_in[1];
    const float* nbi = (const float*)d_in[2];
    const float* wq  = (const float*)d_in[3];
    const float* bq  = (const float*)d_in[4];
    const float* wk  = (const float*)d_in[5];
    const float* bk  = (const float*)d_in[6];
    const float* wv  = (const float*)d_in[7];
    const float* bv  = (const float*)d_in[8];
    const float* wp  = (const float*)d_in[9];
    const float* bp  = (const float*)d_in[10];
    float* out = (float*)d_out;

    char* ws = (char*)d_ws;
    u16* qb = (u16*)(ws);                        // 32 MB  [32768,512]  (q)
    u16* kb = (u16*)(ws + (32ull << 20));        // 32 MB  [32768,512]  (k)
    u16* vT = (u16*)(ws + (64ull << 20));        // 32 MB  [32,512,1024]
    u16* sb = (u16*)(ws + (96ull << 20));        // 64 MB  [32,1024,1024] (scores)
    u16* hn = (u16*)(ws + (160ull << 20));       // 32 MB  [32768,512]
    u16* ao = hn;                                 // reuse: hn dead after QKV
    u16* wT = (u16*)(ws + (192ull << 20));       // 2 MB   [4*512,512] stacked q,k,v,p
    float2* gnp = (float2*)sb;                   // 64 KB partials (dead before scores)
    float2* gns = (float2*)(ws + (97ull << 20)); // 8 KB stats

    transpose_weights<<<4096, 256, 0, stream>>>(wq, wk, wv, wp, wT);
    gn_partial<<<256, 256, 0, stream>>>(x, gnp);
    gn_stats<<<4, 256, 0, stream>>>(gnp, gns);
    gn_apply<<<16384, 256, 0, stream>>>(x, gns, nsc, nbi, hn);

    const dim3 blk(512);
    // fused QKV: M=32768 (128 strips), N=1536 (6 blocks): 8 XCD * 16 * 6 = 768
    gemm8<4, 6, 1><<<768, blk, 0, stream>>>(hn, wT, qb, vT, bq, bk, bv, nullptr,
                                            512, 512, 0, 0, 0, 1.f);

    const dim3 g2(4, 4, 32);                     // scores: N=1024, M=1024, 32 batches
    gemm8<0, 0, 0><<<g2, blk, 0, stream>>>(qb, kb, sb, nullptr, nullptr, nullptr, nullptr, nullptr,
                                           512, 1024, 1024L * 512, 1024L * 512, 1024L * 1024,
                                           0.04419417382415922f);  // 512^-0.5
    softmax_kernel<<<8192, dim3(256), 0, stream>>>(sb);

    const dim3 g3(2, 4, 32);                     // out: N=512, M=1024, 32 batches
    gemm8<0, 0, 0><<<g3, blk, 0, stream>>>(sb, vT, ao, nullptr, nullptr, nullptr, nullptr, nullptr,
                                           1024, 512, 1024L * 1024, 512L * 1024, 1024L * 512,
                                           1.f);

    // proj: M=32768 (128 strips), N=512 (2 blocks): 8 XCD * 16 * 2 = 256
    gemm8<3, 2, 0><<<256, blk, 0, stream>>>(ao, wT + 3 * 262144, out, nullptr, bp, nullptr, nullptr, x,
                                            512, 512, 0, 0, 0, 1.f);
}